// Round 1
// baseline (301.958 us; speedup 1.0000x reference)
//
#include <hip/hip_runtime.h>

#define NFEAT 256
#define NHID 128
#define NCLASS 32

// ---------------------------------------------------------------- utilities

__global__ __launch_bounds__(1024) void zero_int_kernel(int* __restrict__ p, int n) {
    int i = blockIdx.x * 1024 + threadIdx.x;
    if (i < n) p[i] = 0;
}

// ---------------------------------------------------------------- GEMM1
// h1[N][128] = x[N][256] @ W1[256][128] + b1
// block: 256 threads, tile 64 rows x 128 cols, per-thread 8 rows x 4 cols
__global__ __launch_bounds__(256) void gemm1_kernel(
    const float* __restrict__ x, const float* __restrict__ W1,
    const float* __restrict__ b1, float* __restrict__ h1, int N)
{
    __shared__ float xs[64][20];     // [row][k], pad 16->20 (bank spread, keeps 16B align)
    __shared__ float ws[16][NHID];   // [k][col]
    const int tid = threadIdx.x;
    const int row0 = blockIdx.x * 64;
    const int rg = tid >> 5;   // 0..7 -> rows rg*8 .. rg*8+7
    const int cg = tid & 31;   // cols cg*4 .. cg*4+3

    float acc[8][4];
#pragma unroll
    for (int i = 0; i < 8; ++i)
#pragma unroll
        for (int j = 0; j < 4; ++j) acc[i][j] = 0.f;

    for (int k0 = 0; k0 < NFEAT; k0 += 16) {
        // stage x tile: 64x16, 4 elems/thread, coalesced 64B per 16 lanes
#pragma unroll
        for (int j = 0; j < 4; ++j) {
            int idx = tid + j * 256;
            int r = idx >> 4, kk = idx & 15;
            int row = row0 + r;
            xs[r][kk] = (row < N) ? x[(size_t)row * NFEAT + k0 + kk] : 0.f;
        }
        // stage W tile: 16x128, 8 elems/thread, coalesced
#pragma unroll
        for (int j = 0; j < 8; ++j) {
            int idx = tid + j * 256;
            int kk = idx >> 7, c = idx & 127;
            ws[kk][c] = W1[(size_t)(k0 + kk) * NHID + c];
        }
        __syncthreads();

#pragma unroll
        for (int kk = 0; kk < 16; kk += 4) {
            float wvf[4][4];
#pragma unroll
            for (int q = 0; q < 4; ++q) {
                float4 t = *(const float4*)&ws[kk + q][cg * 4];
                wvf[q][0] = t.x; wvf[q][1] = t.y; wvf[q][2] = t.z; wvf[q][3] = t.w;
            }
#pragma unroll
            for (int i = 0; i < 8; ++i) {
                float4 xt = *(const float4*)&xs[rg * 8 + i][kk];
                float xf[4] = {xt.x, xt.y, xt.z, xt.w};
#pragma unroll
                for (int q = 0; q < 4; ++q)
#pragma unroll
                    for (int j = 0; j < 4; ++j)
                        acc[i][j] += xf[q] * wvf[q][j];
            }
        }
        __syncthreads();
    }

    float4 bv = *(const float4*)&b1[cg * 4];
#pragma unroll
    for (int i = 0; i < 8; ++i) {
        int row = row0 + rg * 8 + i;
        if (row < N) {
            float4 o = make_float4(acc[i][0] + bv.x, acc[i][1] + bv.y,
                                   acc[i][2] + bv.z, acc[i][3] + bv.w);
            *(float4*)&h1[(size_t)row * NHID + cg * 4] = o;
        }
    }
}

// ---------------------------------------------------------------- CSR build

__global__ __launch_bounds__(256) void hist_kernel(const int* __restrict__ dst,
                                                   int* __restrict__ counts, int E) {
    int e = blockIdx.x * 256 + threadIdx.x;
    if (e < E) atomicAdd(&counts[dst[e]], 1);
}

__global__ __launch_bounds__(256) void scan_partial_kernel(const int* __restrict__ counts,
                                                           int* __restrict__ partial, int N) {
    __shared__ int s[256];
    int i = blockIdx.x * 256 + threadIdx.x;
    int v = (i < N) ? counts[i] : 0;
    s[threadIdx.x] = v;
    __syncthreads();
    for (int off = 128; off > 0; off >>= 1) {
        if (threadIdx.x < off) s[threadIdx.x] += s[threadIdx.x + off];
        __syncthreads();
    }
    if (threadIdx.x == 0) partial[blockIdx.x] = s[0];
}

// single block: exclusive scan of per-chunk sums (nchunks <= 256)
__global__ __launch_bounds__(256) void scan_chunk_kernel(const int* __restrict__ partial,
                                                         int* __restrict__ chunk_off,
                                                         int nchunks,
                                                         int* __restrict__ row_ptr, int N) {
    __shared__ int s[256];
    int t = threadIdx.x;
    int v = (t < nchunks) ? partial[t] : 0;
    s[t] = v;
    __syncthreads();
    for (int off = 1; off < 256; off <<= 1) {
        int tv = (t >= off) ? s[t - off] : 0;
        __syncthreads();
        s[t] += tv;
        __syncthreads();
    }
    if (t < nchunks) chunk_off[t] = s[t] - v;
    if (t == 255) row_ptr[N] = s[255];   // total == E
}

__global__ __launch_bounds__(256) void scan_final_kernel(const int* __restrict__ counts,
                                                         const int* __restrict__ chunk_off,
                                                         int* __restrict__ row_ptr,
                                                         int* __restrict__ cursor, int N) {
    __shared__ int s[256];
    int t = threadIdx.x;
    int i = blockIdx.x * 256 + t;
    int v = (i < N) ? counts[i] : 0;
    s[t] = v;
    __syncthreads();
    for (int off = 1; off < 256; off <<= 1) {
        int tv = (t >= off) ? s[t - off] : 0;
        __syncthreads();
        s[t] += tv;
        __syncthreads();
    }
    if (i < N) {
        int excl = chunk_off[blockIdx.x] + s[t] - v;
        row_ptr[i] = excl;
        cursor[i] = excl;
    }
}

__global__ __launch_bounds__(256) void scatter_kernel(const int* __restrict__ src,
                                                      const int* __restrict__ dst,
                                                      const float* __restrict__ w,
                                                      int* __restrict__ cursor,
                                                      int* __restrict__ csr_src,
                                                      float* __restrict__ csr_w, int E) {
    int e = blockIdx.x * 256 + threadIdx.x;
    if (e < E) {
        int d = dst[e];
        int pos = atomicAdd(&cursor[d], 1);
        csr_src[pos] = src[e];
        csr_w[pos] = w[e];
    }
}

// ---------------------------------------------------------------- SpMM1 + ReLU
// h1s[dst] = relu( sum_e w_e * h1[src_e] ), F=128; one wave per dst row
__global__ __launch_bounds__(256) void spmm1_relu_kernel(
    const int* __restrict__ row_ptr, const int* __restrict__ csr_src,
    const float* __restrict__ csr_w, const float* __restrict__ h1,
    float* __restrict__ h1s, int N)
{
    const int lane = threadIdx.x & 63;
    const int wid = threadIdx.x >> 6;
    const int row = blockIdx.x * 4 + wid;
    if (row >= N) return;
    const int e0 = row_ptr[row], e1 = row_ptr[row + 1];
    float a0 = 0.f, a1 = 0.f;
    for (int e = e0; e < e1; ++e) {
        int s = csr_src[e];
        float w = csr_w[e];
        const float* hp = &h1[(size_t)s * NHID];
        a0 += w * hp[lane];
        a1 += w * hp[lane + 64];
    }
    h1s[(size_t)row * NHID + lane] = fmaxf(a0, 0.f);
    h1s[(size_t)row * NHID + lane + 64] = fmaxf(a1, 0.f);
}

// ---------------------------------------------------------------- GEMM2
// h2[N][32] = h1s[N][128] @ W2[128][32] + b2
// block: 256 threads, 32 rows; per-thread 1 row x 4 cols
__global__ __launch_bounds__(256) void gemm2_kernel(
    const float* __restrict__ h1s, const float* __restrict__ W2,
    const float* __restrict__ b2, float* __restrict__ h2, int N)
{
    __shared__ float hs[32][132];        // pad 128->132: conflict-free + 16B align
    __shared__ float w2s[NHID * NCLASS]; // 16 KB, [k][c]
    const int tid = threadIdx.x;
#pragma unroll
    for (int j = 0; j < 16; ++j) {
        int idx = tid + j * 256;
        w2s[idx] = W2[idx];
    }
    const int row0 = blockIdx.x * 32;
#pragma unroll
    for (int j = 0; j < 4; ++j) {
        int idx = tid + j * 256;       // float4 units
        int r = idx >> 5, c4 = idx & 31;
        int row = row0 + r;
        float4 v = (row < N) ? *(const float4*)&h1s[(size_t)row * NHID + c4 * 4]
                             : make_float4(0.f, 0.f, 0.f, 0.f);
        *(float4*)&hs[r][c4 * 4] = v;
    }
    __syncthreads();

    const int rl = tid >> 3;   // 0..31
    const int cgp = tid & 7;   // cols cgp*4..+3
    float4 bv = *(const float4*)&b2[cgp * 4];
    float acc[4] = {bv.x, bv.y, bv.z, bv.w};
#pragma unroll
    for (int k = 0; k < NHID; k += 4) {
        float4 hv = *(const float4*)&hs[rl][k];
        float hf[4] = {hv.x, hv.y, hv.z, hv.w};
#pragma unroll
        for (int q = 0; q < 4; ++q) {
            float4 wv = *(const float4*)&w2s[(k + q) * NCLASS + cgp * 4];
            acc[0] += hf[q] * wv.x;
            acc[1] += hf[q] * wv.y;
            acc[2] += hf[q] * wv.z;
            acc[3] += hf[q] * wv.w;
        }
    }
    int row = row0 + rl;
    if (row < N)
        *(float4*)&h2[(size_t)row * NCLASS + cgp * 4] =
            make_float4(acc[0], acc[1], acc[2], acc[3]);
}

// ---------------------------------------------------------------- SpMM2
// out[dst] = sum_e w_e * h2[src_e], F=32; 32 lanes per dst row
__global__ __launch_bounds__(256) void spmm2_kernel(
    const int* __restrict__ row_ptr, const int* __restrict__ csr_src,
    const float* __restrict__ csr_w, const float* __restrict__ h2,
    float* __restrict__ out, int N)
{
    const int c = threadIdx.x & 31;
    const int rl = threadIdx.x >> 5;   // 0..7
    const int row = blockIdx.x * 8 + rl;
    if (row >= N) return;
    const int e0 = row_ptr[row], e1 = row_ptr[row + 1];
    float a = 0.f;
    for (int e = e0; e < e1; ++e) {
        int s = csr_src[e];
        float w = csr_w[e];
        a += w * h2[(size_t)s * NCLASS + c];
    }
    out[(size_t)row * NCLASS + c] = a;
}

// ---------------------------------------------------------------- launch

extern "C" void kernel_launch(void* const* d_in, const int* in_sizes, int n_in,
                              void* d_out, int out_size, void* d_ws, size_t ws_size,
                              hipStream_t stream) {
    const float* x    = (const float*)d_in[0];
    const int*   esrc = (const int*)d_in[1];
    const int*   edst = (const int*)d_in[2];
    const float* ew   = (const float*)d_in[3];
    const float* W1   = (const float*)d_in[4];
    const float* b1   = (const float*)d_in[5];
    const float* W2   = (const float*)d_in[6];
    const float* b2   = (const float*)d_in[7];
    float* out = (float*)d_out;

    const int N = in_sizes[0] / NFEAT;
    const int E = in_sizes[1];

    char* base = (char*)d_ws;
    size_t off = 0;
    auto take = [&](size_t bytes) -> void* {
        void* p = base + off;
        off += (bytes + 255) & ~(size_t)255;
        return p;
    };
    float* h1      = (float*)take((size_t)N * NHID * sizeof(float));
    float* h1s     = (float*)take((size_t)N * NHID * sizeof(float));
    float* h2      = (float*)take((size_t)N * NCLASS * sizeof(float));
    int*   row_ptr = (int*)take((size_t)(N + 1) * sizeof(int));
    int*   cursor  = (int*)take((size_t)N * sizeof(int));
    int*   counts  = (int*)take((size_t)N * sizeof(int));
    int*   partial = (int*)take(256 * sizeof(int));
    int*   chunkoff= (int*)take(256 * sizeof(int));
    int*   csr_src = (int*)take((size_t)E * sizeof(int));
    float* csr_w   = (float*)take((size_t)E * sizeof(float));
    (void)ws_size; (void)n_in; (void)out_size;

    const int nchunks = (N + 255) / 256;   // 196 for N=50000, must be <= 256

    // CSR build + layer-1 GEMM (independent; stream-serial is fine)
    zero_int_kernel<<<(N + 1023) / 1024, 1024, 0, stream>>>(counts, N);
    gemm1_kernel<<<(N + 63) / 64, 256, 0, stream>>>(x, W1, b1, h1, N);
    hist_kernel<<<(E + 255) / 256, 256, 0, stream>>>(edst, counts, E);
    scan_partial_kernel<<<nchunks, 256, 0, stream>>>(counts, partial, N);
    scan_chunk_kernel<<<1, 256, 0, stream>>>(partial, chunkoff, nchunks, row_ptr, N);
    scan_final_kernel<<<nchunks, 256, 0, stream>>>(counts, chunkoff, row_ptr, cursor, N);
    scatter_kernel<<<(E + 255) / 256, 256, 0, stream>>>(esrc, edst, ew, cursor,
                                                        csr_src, csr_w, E);
    // layer 1 SpMM + ReLU
    spmm1_relu_kernel<<<(N + 3) / 4, 256, 0, stream>>>(row_ptr, csr_src, csr_w, h1, h1s, N);
    // layer 2
    gemm2_kernel<<<(N + 31) / 32, 256, 0, stream>>>(h1s, W2, b2, h2, N);
    spmm2_kernel<<<(N + 7) / 8, 256, 0, stream>>>(row_ptr, csr_src, csr_w, h2, out, N);
}

// Round 2
// 253.437 us; speedup vs baseline: 1.1915x; 1.1915x over previous
//
#include <hip/hip_runtime.h>

#define NFEAT 256
#define NHID 128
#define NCLASS 32

static __device__ __forceinline__ unsigned short f2bf(float f) {
    unsigned u = __float_as_uint(f);
    unsigned r = (u + 0x7fffu + ((u >> 16) & 1u)) >> 16;   // RNE
    return (unsigned short)r;
}
static __device__ __forceinline__ float bf_lo(unsigned d) {  // low 2 bytes -> f32
    return __uint_as_float(d << 16);
}
static __device__ __forceinline__ float bf_hi(unsigned d) {  // high 2 bytes -> f32
    return __uint_as_float(d & 0xffff0000u);
}

// ---------------------------------------------------------------- utilities

__global__ __launch_bounds__(1024) void zero_int_kernel(int* __restrict__ p, int n) {
    int i = blockIdx.x * 1024 + threadIdx.x;
    if (i < n) p[i] = 0;
}

// ---------------------------------------------------------------- GEMM1
// h1[N][128] = bf16( x[N][256] @ W1[256][128] + b1 )
__global__ __launch_bounds__(256) void gemm1_kernel(
    const float* __restrict__ x, const float* __restrict__ W1,
    const float* __restrict__ b1, unsigned short* __restrict__ h1b, int N)
{
    __shared__ float xs[64][20];     // [row][k], pad 16->20
    __shared__ float ws[16][NHID];   // [k][col]
    const int tid = threadIdx.x;
    const int row0 = blockIdx.x * 64;
    const int rg = tid >> 5;   // 0..7 -> rows rg*8 .. rg*8+7
    const int cg = tid & 31;   // cols cg*4 .. cg*4+3

    float acc[8][4];
#pragma unroll
    for (int i = 0; i < 8; ++i)
#pragma unroll
        for (int j = 0; j < 4; ++j) acc[i][j] = 0.f;

    for (int k0 = 0; k0 < NFEAT; k0 += 16) {
#pragma unroll
        for (int j = 0; j < 4; ++j) {
            int idx = tid + j * 256;
            int r = idx >> 4, kk = idx & 15;
            int row = row0 + r;
            xs[r][kk] = (row < N) ? x[(size_t)row * NFEAT + k0 + kk] : 0.f;
        }
#pragma unroll
        for (int j = 0; j < 8; ++j) {
            int idx = tid + j * 256;
            int kk = idx >> 7, c = idx & 127;
            ws[kk][c] = W1[(size_t)(k0 + kk) * NHID + c];
        }
        __syncthreads();

#pragma unroll
        for (int kk = 0; kk < 16; kk += 4) {
            float wvf[4][4];
#pragma unroll
            for (int q = 0; q < 4; ++q) {
                float4 t = *(const float4*)&ws[kk + q][cg * 4];
                wvf[q][0] = t.x; wvf[q][1] = t.y; wvf[q][2] = t.z; wvf[q][3] = t.w;
            }
#pragma unroll
            for (int i = 0; i < 8; ++i) {
                float4 xt = *(const float4*)&xs[rg * 8 + i][kk];
                float xf[4] = {xt.x, xt.y, xt.z, xt.w};
#pragma unroll
                for (int q = 0; q < 4; ++q)
#pragma unroll
                    for (int j = 0; j < 4; ++j)
                        acc[i][j] += xf[q] * wvf[q][j];
            }
        }
        __syncthreads();
    }

    float4 bv = *(const float4*)&b1[cg * 4];
#pragma unroll
    for (int i = 0; i < 8; ++i) {
        int row = row0 + rg * 8 + i;
        if (row < N) {
            ushort4 o;
            o.x = f2bf(acc[i][0] + bv.x);
            o.y = f2bf(acc[i][1] + bv.y);
            o.z = f2bf(acc[i][2] + bv.z);
            o.w = f2bf(acc[i][3] + bv.w);
            *(ushort4*)&h1b[(size_t)row * NHID + cg * 4] = o;
        }
    }
}

// ---------------------------------------------------------------- CSR build

__global__ __launch_bounds__(256) void hist_kernel(const int* __restrict__ dst,
                                                   int* __restrict__ counts, int E) {
    int e = blockIdx.x * 256 + threadIdx.x;
    if (e < E) atomicAdd(&counts[dst[e]], 1);
}

__global__ __launch_bounds__(256) void scan_partial_kernel(const int* __restrict__ counts,
                                                           int* __restrict__ partial, int N) {
    __shared__ int s[256];
    int i = blockIdx.x * 256 + threadIdx.x;
    int v = (i < N) ? counts[i] : 0;
    s[threadIdx.x] = v;
    __syncthreads();
    for (int off = 128; off > 0; off >>= 1) {
        if (threadIdx.x < off) s[threadIdx.x] += s[threadIdx.x + off];
        __syncthreads();
    }
    if (threadIdx.x == 0) partial[blockIdx.x] = s[0];
}

__global__ __launch_bounds__(256) void scan_chunk_kernel(const int* __restrict__ partial,
                                                         int* __restrict__ chunk_off,
                                                         int nchunks,
                                                         int* __restrict__ row_ptr, int N) {
    __shared__ int s[256];
    int t = threadIdx.x;
    int v = (t < nchunks) ? partial[t] : 0;
    s[t] = v;
    __syncthreads();
    for (int off = 1; off < 256; off <<= 1) {
        int tv = (t >= off) ? s[t - off] : 0;
        __syncthreads();
        s[t] += tv;
        __syncthreads();
    }
    if (t < nchunks) chunk_off[t] = s[t] - v;
    if (t == 255) row_ptr[N] = s[255];
}

__global__ __launch_bounds__(256) void scan_final_kernel(const int* __restrict__ counts,
                                                         const int* __restrict__ chunk_off,
                                                         int* __restrict__ row_ptr,
                                                         int* __restrict__ cursor, int N) {
    __shared__ int s[256];
    int t = threadIdx.x;
    int i = blockIdx.x * 256 + t;
    int v = (i < N) ? counts[i] : 0;
    s[t] = v;
    __syncthreads();
    for (int off = 1; off < 256; off <<= 1) {
        int tv = (t >= off) ? s[t - off] : 0;
        __syncthreads();
        s[t] += tv;
        __syncthreads();
    }
    if (i < N) {
        int excl = chunk_off[blockIdx.x] + s[t] - v;
        row_ptr[i] = excl;
        cursor[i] = excl;
    }
}

__global__ __launch_bounds__(256) void scatter_kernel(const int* __restrict__ src,
                                                      const int* __restrict__ dst,
                                                      const float* __restrict__ w,
                                                      int* __restrict__ cursor,
                                                      int* __restrict__ csr_src,
                                                      float* __restrict__ csr_w, int E) {
    int e = blockIdx.x * 256 + threadIdx.x;
    if (e < E) {
        int d = dst[e];
        int pos = atomicAdd(&cursor[d], 1);
        csr_src[pos] = src[e];
        csr_w[pos] = w[e];
    }
}

// ---------------------------------------------------------------- SpMM1 + ReLU
// h1s[dst] = relu( sum_e w_e * h1b[src_e] ); h1b bf16 [N][128]; one wave per row.
// Lane i covers elements 2i, 2i+1 (one dword of bf16 pair per edge).
__global__ __launch_bounds__(256) void spmm1_relu_kernel(
    const int* __restrict__ row_ptr, const int* __restrict__ csr_src,
    const float* __restrict__ csr_w, const unsigned short* __restrict__ h1b,
    float* __restrict__ h1s, int N)
{
    const int lane = threadIdx.x & 63;
    const int wid = threadIdx.x >> 6;
    const int row = blockIdx.x * 4 + wid;
    if (row >= N) return;
    const int e0 = row_ptr[row], e1 = row_ptr[row + 1];
    const size_t loff = (size_t)(lane * 2);
    float a0 = 0.f, a1 = 0.f;
    int e = e0;
    for (; e + 4 <= e1; e += 4) {
        int s0 = csr_src[e], s1 = csr_src[e + 1], s2 = csr_src[e + 2], s3 = csr_src[e + 3];
        float w0 = csr_w[e], w1 = csr_w[e + 1], w2 = csr_w[e + 2], w3 = csr_w[e + 3];
        unsigned d0 = *(const unsigned*)(h1b + (size_t)s0 * NHID + loff);
        unsigned d1 = *(const unsigned*)(h1b + (size_t)s1 * NHID + loff);
        unsigned d2 = *(const unsigned*)(h1b + (size_t)s2 * NHID + loff);
        unsigned d3 = *(const unsigned*)(h1b + (size_t)s3 * NHID + loff);
        a0 += w0 * bf_lo(d0); a1 += w0 * bf_hi(d0);
        a0 += w1 * bf_lo(d1); a1 += w1 * bf_hi(d1);
        a0 += w2 * bf_lo(d2); a1 += w2 * bf_hi(d2);
        a0 += w3 * bf_lo(d3); a1 += w3 * bf_hi(d3);
    }
    for (; e < e1; ++e) {
        int s = csr_src[e];
        float w = csr_w[e];
        unsigned d = *(const unsigned*)(h1b + (size_t)s * NHID + loff);
        a0 += w * bf_lo(d); a1 += w * bf_hi(d);
    }
    float2 o = make_float2(fmaxf(a0, 0.f), fmaxf(a1, 0.f));
    *(float2*)&h1s[(size_t)row * NHID + lane * 2] = o;
}

// ---------------------------------------------------------------- GEMM2
// h2[N][32] = h1s[N][128] @ W2[128][32] + b2  (fp32 in/out)
__global__ __launch_bounds__(256) void gemm2_kernel(
    const float* __restrict__ h1s, const float* __restrict__ W2,
    const float* __restrict__ b2, float* __restrict__ h2, int N)
{
    __shared__ float hs[32][132];
    __shared__ float w2s[NHID * NCLASS];
    const int tid = threadIdx.x;
#pragma unroll
    for (int j = 0; j < 16; ++j) {
        int idx = tid + j * 256;
        w2s[idx] = W2[idx];
    }
    const int row0 = blockIdx.x * 32;
#pragma unroll
    for (int j = 0; j < 4; ++j) {
        int idx = tid + j * 256;
        int r = idx >> 5, c4 = idx & 31;
        int row = row0 + r;
        float4 v = (row < N) ? *(const float4*)&h1s[(size_t)row * NHID + c4 * 4]
                             : make_float4(0.f, 0.f, 0.f, 0.f);
        *(float4*)&hs[r][c4 * 4] = v;
    }
    __syncthreads();

    const int rl = tid >> 3;
    const int cgp = tid & 7;
    float4 bv = *(const float4*)&b2[cgp * 4];
    float acc[4] = {bv.x, bv.y, bv.z, bv.w};
#pragma unroll
    for (int k = 0; k < NHID; k += 4) {
        float4 hv = *(const float4*)&hs[rl][k];
        float hf[4] = {hv.x, hv.y, hv.z, hv.w};
#pragma unroll
        for (int q = 0; q < 4; ++q) {
            float4 wv = *(const float4*)&w2s[(k + q) * NCLASS + cgp * 4];
            acc[0] += hf[q] * wv.x;
            acc[1] += hf[q] * wv.y;
            acc[2] += hf[q] * wv.z;
            acc[3] += hf[q] * wv.w;
        }
    }
    int row = row0 + rl;
    if (row < N)
        *(float4*)&h2[(size_t)row * NCLASS + cgp * 4] =
            make_float4(acc[0], acc[1], acc[2], acc[3]);
}

// ---------------------------------------------------------------- SpMM2
// out[dst] = sum_e w_e * h2[src_e], F=32 fp32; 32 lanes per dst row
__global__ __launch_bounds__(256) void spmm2_kernel(
    const int* __restrict__ row_ptr, const int* __restrict__ csr_src,
    const float* __restrict__ csr_w, const float* __restrict__ h2,
    float* __restrict__ out, int N)
{
    const int c = threadIdx.x & 31;
    const int rl = threadIdx.x >> 5;
    const int row = blockIdx.x * 8 + rl;
    if (row >= N) return;
    const int e0 = row_ptr[row], e1 = row_ptr[row + 1];
    float a = 0.f;
    int e = e0;
    for (; e + 4 <= e1; e += 4) {
        int s0 = csr_src[e], s1 = csr_src[e + 1], s2 = csr_src[e + 2], s3 = csr_src[e + 3];
        float w0 = csr_w[e], w1 = csr_w[e + 1], w2 = csr_w[e + 2], w3 = csr_w[e + 3];
        float v0 = h2[(size_t)s0 * NCLASS + c];
        float v1 = h2[(size_t)s1 * NCLASS + c];
        float v2 = h2[(size_t)s2 * NCLASS + c];
        float v3 = h2[(size_t)s3 * NCLASS + c];
        a += w0 * v0 + w1 * v1 + w2 * v2 + w3 * v3;
    }
    for (; e < e1; ++e) {
        int s = csr_src[e];
        a += csr_w[e] * h2[(size_t)s * NCLASS + c];
    }
    out[(size_t)row * NCLASS + c] = a;
}

// ---------------------------------------------------------------- launch

extern "C" void kernel_launch(void* const* d_in, const int* in_sizes, int n_in,
                              void* d_out, int out_size, void* d_ws, size_t ws_size,
                              hipStream_t stream) {
    const float* x    = (const float*)d_in[0];
    const int*   esrc = (const int*)d_in[1];
    const int*   edst = (const int*)d_in[2];
    const float* ew   = (const float*)d_in[3];
    const float* W1   = (const float*)d_in[4];
    const float* b1   = (const float*)d_in[5];
    const float* W2   = (const float*)d_in[6];
    const float* b2   = (const float*)d_in[7];
    float* out = (float*)d_out;

    const int N = in_sizes[0] / NFEAT;
    const int E = in_sizes[1];

    char* base = (char*)d_ws;
    size_t off = 0;
    auto take = [&](size_t bytes) -> void* {
        void* p = base + off;
        off += (bytes + 255) & ~(size_t)255;
        return p;
    };
    unsigned short* h1b = (unsigned short*)take((size_t)N * NHID * sizeof(unsigned short));
    float* h1s     = (float*)take((size_t)N * NHID * sizeof(float));
    float* h2      = (float*)take((size_t)N * NCLASS * sizeof(float));
    int*   row_ptr = (int*)take((size_t)(N + 1) * sizeof(int));
    int*   cursor  = (int*)take((size_t)N * sizeof(int));
    int*   counts  = (int*)take((size_t)N * sizeof(int));
    int*   partial = (int*)take(256 * sizeof(int));
    int*   chunkoff= (int*)take(256 * sizeof(int));
    int*   csr_src = (int*)take((size_t)E * sizeof(int));
    float* csr_w   = (float*)take((size_t)E * sizeof(float));
    (void)ws_size; (void)n_in; (void)out_size;

    const int nchunks = (N + 255) / 256;

    zero_int_kernel<<<(N + 1023) / 1024, 1024, 0, stream>>>(counts, N);
    gemm1_kernel<<<(N + 63) / 64, 256, 0, stream>>>(x, W1, b1, h1b, N);
    hist_kernel<<<(E + 255) / 256, 256, 0, stream>>>(edst, counts, E);
    scan_partial_kernel<<<nchunks, 256, 0, stream>>>(counts, partial, N);
    scan_chunk_kernel<<<1, 256, 0, stream>>>(partial, chunkoff, nchunks, row_ptr, N);
    scan_final_kernel<<<nchunks, 256, 0, stream>>>(counts, chunkoff, row_ptr, cursor, N);
    scatter_kernel<<<(E + 255) / 256, 256, 0, stream>>>(esrc, edst, ew, cursor,
                                                        csr_src, csr_w, E);
    spmm1_relu_kernel<<<(N + 3) / 4, 256, 0, stream>>>(row_ptr, csr_src, csr_w, h1b, h1s, N);
    gemm2_kernel<<<(N + 31) / 32, 256, 0, stream>>>(h1s, W2, b2, h2, N);
    spmm2_kernel<<<(N + 7) / 8, 256, 0, stream>>>(row_ptr, csr_src, csr_w, h2, out, N);
}

// Round 3
// 209.673 us; speedup vs baseline: 1.4401x; 1.2087x over previous
//
#include <hip/hip_runtime.h>

#define NFEAT 256
#define NHID 128
#define NCLASS 32

typedef __attribute__((ext_vector_type(8))) short short8;
typedef __attribute__((ext_vector_type(4))) float f32x4;
typedef __attribute__((ext_vector_type(4))) int int4v;

static __device__ __forceinline__ unsigned short f2bf(float f) {
    unsigned u = __float_as_uint(f);
    unsigned r = (u + 0x7fffu + ((u >> 16) & 1u)) >> 16;   // RNE
    return (unsigned short)r;
}
static __device__ __forceinline__ float bf_lo(unsigned d) {
    return __uint_as_float(d << 16);
}
static __device__ __forceinline__ float bf_hi(unsigned d) {
    return __uint_as_float(d & 0xffff0000u);
}

// ---------------------------------------------------------------- utilities

__global__ __launch_bounds__(1024) void zero_int_kernel(int* __restrict__ p, int n) {
    int i = blockIdx.x * 1024 + threadIdx.x;
    if (i < n) p[i] = 0;
}

// W1 fp32 [256 k][128 c]  ->  W1t bf16 [128 c][256 k]  (one-time, 128 KB)
__global__ __launch_bounds__(256) void precast_w1_kernel(const float* __restrict__ W1,
                                                         unsigned short* __restrict__ W1t) {
    int o = blockIdx.x * 256 + threadIdx.x;      // 32768 outputs
    int c = o >> 8, k = o & 255;
    W1t[o] = f2bf(W1[(size_t)k * NHID + c]);
}

// ---------------------------------------------------------------- GEMM1 (MFMA bf16)
// h1b[N][128] = bf16( x[N][256] @ W1[256][128] + b1 )
// block: 256 thr (4 waves), 64 rows x 128 cols; W1t fully in LDS (swizzled),
// x staged per 64-K tile fp32->bf16 (swizzled). mfma_f32_16x16x32_bf16.
__global__ __launch_bounds__(256) void gemm1_mfma_kernel(
    const float* __restrict__ x, const unsigned short* __restrict__ W1t,
    const float* __restrict__ b1, unsigned short* __restrict__ h1b, int N)
{
    __shared__ unsigned short wt[128 * 256];   // 64 KB: [c][k], 16B-slot swizzled
    __shared__ unsigned short xs[64 * 64];     // 8 KB:  [r][k], 16B-slot swizzled

    const int tid = threadIdx.x;
    const int lane = tid & 63;
    const int wv = tid >> 6;                   // wave 0..3 -> rows wv*16..+15
    const int row0 = blockIdx.x * 64;
    const int l15 = lane & 15;
    const int l47 = lane >> 4;                 // 0..3
    const int r7 = lane & 7;                   // == (c or r row)&7 for frag reads

    // ---- stage all of W1t into LDS (4096 16B slots, 16 per thread)
    {
        const int4v* src = (const int4v*)W1t;
#pragma unroll
        for (int j = 0; j < 16; ++j) {
            int si = tid + j * 256;
            int c = si >> 5, s = si & 31;
            int sp = (s & 24) | ((s & 7) ^ (c & 7));
            int4v v = src[si];
            *(int4v*)&wt[c * 256 + sp * 8] = v;
        }
    }

    // ---- x stager: tile t covers k = t*64 .. t*64+63; 512 slots, 2 per thread
    auto stage_x = [&](int t) {
#pragma unroll
        for (int j = 0; j < 2; ++j) {
            int si = tid + j * 256;
            int r = si >> 3, s = si & 7;
            int row = row0 + r;
            float4 v0 = make_float4(0.f, 0.f, 0.f, 0.f), v1 = v0;
            if (row < N) {
                const float4* xp = (const float4*)&x[(size_t)row * NFEAT + t * 64 + s * 8];
                v0 = xp[0]; v1 = xp[1];
            }
            int w0 = f2bf(v0.x) | ((unsigned)f2bf(v0.y) << 16);
            int w1 = f2bf(v0.z) | ((unsigned)f2bf(v0.w) << 16);
            int w2 = f2bf(v1.x) | ((unsigned)f2bf(v1.y) << 16);
            int w3 = f2bf(v1.z) | ((unsigned)f2bf(v1.w) << 16);
            int sp = s ^ (r & 7);
            int4v pv; pv[0] = w0; pv[1] = w1; pv[2] = w2; pv[3] = w3;
            *(int4v*)&xs[r * 64 + sp * 8] = pv;
        }
    };

    f32x4 acc[8];
#pragma unroll
    for (int cf = 0; cf < 8; ++cf)
#pragma unroll
        for (int r = 0; r < 4; ++r) acc[cf][r] = 0.f;

    stage_x(0);
    __syncthreads();

    const int arow = wv * 16 + l15;            // (arow & 7) == r7
#pragma unroll
    for (int t = 0; t < 4; ++t) {
        short8 af[2];
#pragma unroll
        for (int kf = 0; kf < 2; ++kf) {
            int slot = (kf * 4 + l47) ^ r7;
            af[kf] = *(const short8*)&xs[arow * 64 + slot * 8];
        }
#pragma unroll
        for (int cf = 0; cf < 8; ++cf) {
            const int brow = cf * 16 + l15;    // (brow & 7) == r7
#pragma unroll
            for (int kf = 0; kf < 2; ++kf) {
                int slot = t * 8 + ((kf * 4 + l47) ^ r7);
                short8 bfr = *(const short8*)&wt[brow * 256 + slot * 8];
                acc[cf] = __builtin_amdgcn_mfma_f32_16x16x32_bf16(af[kf], bfr, acc[cf], 0, 0, 0);
            }
        }
        __syncthreads();
        if (t < 3) {
            stage_x(t + 1);
            __syncthreads();
        }
    }

    // epilogue: D row=(lane>>4)*4+r, col=lane&15 (per-frag)
#pragma unroll
    for (int cf = 0; cf < 8; ++cf) {
        float bias = b1[cf * 16 + l15];
#pragma unroll
        for (int r = 0; r < 4; ++r) {
            int row = row0 + wv * 16 + l47 * 4 + r;
            if (row < N)
                h1b[(size_t)row * NHID + cf * 16 + l15] = f2bf(acc[cf][r] + bias);
        }
    }
}

// ---------------------------------------------------------------- CSR build

__global__ __launch_bounds__(256) void hist_kernel(const int* __restrict__ dst,
                                                   int* __restrict__ counts, int E) {
    int e = blockIdx.x * 256 + threadIdx.x;
    if (e < E) atomicAdd(&counts[dst[e]], 1);
}

__global__ __launch_bounds__(256) void scan_partial_kernel(const int* __restrict__ counts,
                                                           int* __restrict__ partial, int N) {
    __shared__ int s[256];
    int i = blockIdx.x * 256 + threadIdx.x;
    int v = (i < N) ? counts[i] : 0;
    s[threadIdx.x] = v;
    __syncthreads();
    for (int off = 128; off > 0; off >>= 1) {
        if (threadIdx.x < off) s[threadIdx.x] += s[threadIdx.x + off];
        __syncthreads();
    }
    if (threadIdx.x == 0) partial[blockIdx.x] = s[0];
}

__global__ __launch_bounds__(256) void scan_chunk_kernel(const int* __restrict__ partial,
                                                         int* __restrict__ chunk_off,
                                                         int nchunks,
                                                         int* __restrict__ row_ptr, int N) {
    __shared__ int s[256];
    int t = threadIdx.x;
    int v = (t < nchunks) ? partial[t] : 0;
    s[t] = v;
    __syncthreads();
    for (int off = 1; off < 256; off <<= 1) {
        int tv = (t >= off) ? s[t - off] : 0;
        __syncthreads();
        s[t] += tv;
        __syncthreads();
    }
    if (t < nchunks) chunk_off[t] = s[t] - v;
    if (t == 255) row_ptr[N] = s[255];
}

__global__ __launch_bounds__(256) void scan_final_kernel(const int* __restrict__ counts,
                                                         const int* __restrict__ chunk_off,
                                                         int* __restrict__ row_ptr,
                                                         int* __restrict__ cursor, int N) {
    __shared__ int s[256];
    int t = threadIdx.x;
    int i = blockIdx.x * 256 + t;
    int v = (i < N) ? counts[i] : 0;
    s[t] = v;
    __syncthreads();
    for (int off = 1; off < 256; off <<= 1) {
        int tv = (t >= off) ? s[t - off] : 0;
        __syncthreads();
        s[t] += tv;
        __syncthreads();
    }
    if (i < N) {
        int excl = chunk_off[blockIdx.x] + s[t] - v;
        row_ptr[i] = excl;
        cursor[i] = excl;
    }
}

__global__ __launch_bounds__(256) void scatter_kernel(const int* __restrict__ src,
                                                      const int* __restrict__ dst,
                                                      const float* __restrict__ w,
                                                      int* __restrict__ cursor,
                                                      int* __restrict__ csr_src,
                                                      float* __restrict__ csr_w, int E) {
    int e = blockIdx.x * 256 + threadIdx.x;
    if (e < E) {
        int d = dst[e];
        int pos = atomicAdd(&cursor[d], 1);
        csr_src[pos] = src[e];
        csr_w[pos] = w[e];
    }
}

// ---------------------------------------------------------------- SpMM1 + ReLU
__global__ __launch_bounds__(256) void spmm1_relu_kernel(
    const int* __restrict__ row_ptr, const int* __restrict__ csr_src,
    const float* __restrict__ csr_w, const unsigned short* __restrict__ h1b,
    float* __restrict__ h1s, int N)
{
    const int lane = threadIdx.x & 63;
    const int wid = threadIdx.x >> 6;
    const int row = blockIdx.x * 4 + wid;
    if (row >= N) return;
    const int e0 = row_ptr[row], e1 = row_ptr[row + 1];
    const size_t loff = (size_t)(lane * 2);
    float a0 = 0.f, a1 = 0.f;
    int e = e0;
    for (; e + 4 <= e1; e += 4) {
        int s0 = csr_src[e], s1 = csr_src[e + 1], s2 = csr_src[e + 2], s3 = csr_src[e + 3];
        float w0 = csr_w[e], w1 = csr_w[e + 1], w2 = csr_w[e + 2], w3 = csr_w[e + 3];
        unsigned d0 = *(const unsigned*)(h1b + (size_t)s0 * NHID + loff);
        unsigned d1 = *(const unsigned*)(h1b + (size_t)s1 * NHID + loff);
        unsigned d2 = *(const unsigned*)(h1b + (size_t)s2 * NHID + loff);
        unsigned d3 = *(const unsigned*)(h1b + (size_t)s3 * NHID + loff);
        a0 += w0 * bf_lo(d0); a1 += w0 * bf_hi(d0);
        a0 += w1 * bf_lo(d1); a1 += w1 * bf_hi(d1);
        a0 += w2 * bf_lo(d2); a1 += w2 * bf_hi(d2);
        a0 += w3 * bf_lo(d3); a1 += w3 * bf_hi(d3);
    }
    for (; e < e1; ++e) {
        int s = csr_src[e];
        float w = csr_w[e];
        unsigned d = *(const unsigned*)(h1b + (size_t)s * NHID + loff);
        a0 += w * bf_lo(d); a1 += w * bf_hi(d);
    }
    float2 o = make_float2(fmaxf(a0, 0.f), fmaxf(a1, 0.f));
    *(float2*)&h1s[(size_t)row * NHID + lane * 2] = o;
}

// ---------------------------------------------------------------- GEMM2
__global__ __launch_bounds__(256) void gemm2_kernel(
    const float* __restrict__ h1s, const float* __restrict__ W2,
    const float* __restrict__ b2, float* __restrict__ h2, int N)
{
    __shared__ float hs[32][132];
    __shared__ float w2s[NHID * NCLASS];
    const int tid = threadIdx.x;
#pragma unroll
    for (int j = 0; j < 16; ++j) {
        int idx = tid + j * 256;
        w2s[idx] = W2[idx];
    }
    const int row0 = blockIdx.x * 32;
#pragma unroll
    for (int j = 0; j < 4; ++j) {
        int idx = tid + j * 256;
        int r = idx >> 5, c4 = idx & 31;
        int row = row0 + r;
        float4 v = (row < N) ? *(const float4*)&h1s[(size_t)row * NHID + c4 * 4]
                             : make_float4(0.f, 0.f, 0.f, 0.f);
        *(float4*)&hs[r][c4 * 4] = v;
    }
    __syncthreads();

    const int rl = tid >> 3;
    const int cgp = tid & 7;
    float4 bv = *(const float4*)&b2[cgp * 4];
    float acc[4] = {bv.x, bv.y, bv.z, bv.w};
#pragma unroll
    for (int k = 0; k < NHID; k += 4) {
        float4 hv = *(const float4*)&hs[rl][k];
        float hf[4] = {hv.x, hv.y, hv.z, hv.w};
#pragma unroll
        for (int q = 0; q < 4; ++q) {
            float4 wv = *(const float4*)&w2s[(k + q) * NCLASS + cgp * 4];
            acc[0] += hf[q] * wv.x;
            acc[1] += hf[q] * wv.y;
            acc[2] += hf[q] * wv.z;
            acc[3] += hf[q] * wv.w;
        }
    }
    int row = row0 + rl;
    if (row < N)
        *(float4*)&h2[(size_t)row * NCLASS + cgp * 4] =
            make_float4(acc[0], acc[1], acc[2], acc[3]);
}

// ---------------------------------------------------------------- SpMM2
__global__ __launch_bounds__(256) void spmm2_kernel(
    const int* __restrict__ row_ptr, const int* __restrict__ csr_src,
    const float* __restrict__ csr_w, const float* __restrict__ h2,
    float* __restrict__ out, int N)
{
    const int c = threadIdx.x & 31;
    const int rl = threadIdx.x >> 5;
    const int row = blockIdx.x * 8 + rl;
    if (row >= N) return;
    const int e0 = row_ptr[row], e1 = row_ptr[row + 1];
    float a = 0.f;
    int e = e0;
    for (; e + 4 <= e1; e += 4) {
        int s0 = csr_src[e], s1 = csr_src[e + 1], s2 = csr_src[e + 2], s3 = csr_src[e + 3];
        float w0 = csr_w[e], w1 = csr_w[e + 1], w2 = csr_w[e + 2], w3 = csr_w[e + 3];
        float v0 = h2[(size_t)s0 * NCLASS + c];
        float v1 = h2[(size_t)s1 * NCLASS + c];
        float v2 = h2[(size_t)s2 * NCLASS + c];
        float v3 = h2[(size_t)s3 * NCLASS + c];
        a += w0 * v0 + w1 * v1 + w2 * v2 + w3 * v3;
    }
    for (; e < e1; ++e) {
        int s = csr_src[e];
        a += csr_w[e] * h2[(size_t)s * NCLASS + c];
    }
    out[(size_t)row * NCLASS + c] = a;
}

// ---------------------------------------------------------------- launch

extern "C" void kernel_launch(void* const* d_in, const int* in_sizes, int n_in,
                              void* d_out, int out_size, void* d_ws, size_t ws_size,
                              hipStream_t stream) {
    const float* x    = (const float*)d_in[0];
    const int*   esrc = (const int*)d_in[1];
    const int*   edst = (const int*)d_in[2];
    const float* ew   = (const float*)d_in[3];
    const float* W1   = (const float*)d_in[4];
    const float* b1   = (const float*)d_in[5];
    const float* W2   = (const float*)d_in[6];
    const float* b2   = (const float*)d_in[7];
    float* out = (float*)d_out;

    const int N = in_sizes[0] / NFEAT;
    const int E = in_sizes[1];

    char* base = (char*)d_ws;
    size_t off = 0;
    auto take = [&](size_t bytes) -> void* {
        void* p = base + off;
        off += (bytes + 255) & ~(size_t)255;
        return p;
    };
    unsigned short* h1b = (unsigned short*)take((size_t)N * NHID * sizeof(unsigned short));
    float* h1s     = (float*)take((size_t)N * NHID * sizeof(float));
    float* h2      = (float*)take((size_t)N * NCLASS * sizeof(float));
    int*   row_ptr = (int*)take((size_t)(N + 1) * sizeof(int));
    int*   cursor  = (int*)take((size_t)N * sizeof(int));
    int*   counts  = (int*)take((size_t)N * sizeof(int));
    int*   partial = (int*)take(256 * sizeof(int));
    int*   chunkoff= (int*)take(256 * sizeof(int));
    int*   csr_src = (int*)take((size_t)E * sizeof(int));
    float* csr_w   = (float*)take((size_t)E * sizeof(float));
    unsigned short* W1t = (unsigned short*)take((size_t)NFEAT * NHID * sizeof(unsigned short));
    (void)ws_size; (void)n_in; (void)out_size;

    const int nchunks = (N + 255) / 256;

    zero_int_kernel<<<(N + 1023) / 1024, 1024, 0, stream>>>(counts, N);
    precast_w1_kernel<<<(NFEAT * NHID) / 256, 256, 0, stream>>>(W1, W1t);
    gemm1_mfma_kernel<<<(N + 63) / 64, 256, 0, stream>>>(x, W1t, b1, h1b, N);
    hist_kernel<<<(E + 255) / 256, 256, 0, stream>>>(edst, counts, E);
    scan_partial_kernel<<<nchunks, 256, 0, stream>>>(counts, partial, N);
    scan_chunk_kernel<<<1, 256, 0, stream>>>(partial, chunkoff, nchunks, row_ptr, N);
    scan_final_kernel<<<nchunks, 256, 0, stream>>>(counts, chunkoff, row_ptr, cursor, N);
    scatter_kernel<<<(E + 255) / 256, 256, 0, stream>>>(esrc, edst, ew, cursor,
                                                        csr_src, csr_w, E);
    spmm1_relu_kernel<<<(N + 3) / 4, 256, 0, stream>>>(row_ptr, csr_src, csr_w, h1b, h1s, N);
    gemm2_kernel<<<(N + 31) / 32, 256, 0, stream>>>(h1s, W2, b2, h2, N);
    spmm2_kernel<<<(N + 7) / 8, 256, 0, stream>>>(row_ptr, csr_src, csr_w, h2, out, N);
}

// Round 4
// 199.755 us; speedup vs baseline: 1.5116x; 1.0496x over previous
//
#include <hip/hip_runtime.h>

#define NFEAT 256
#define NHID 128
#define NCLASS 32

typedef __attribute__((ext_vector_type(8))) short short8;
typedef __attribute__((ext_vector_type(4))) float f32x4;
typedef __attribute__((ext_vector_type(4))) int int4v;

static __device__ __forceinline__ unsigned short f2bf(float f) {
    unsigned u = __float_as_uint(f);
    unsigned r = (u + 0x7fffu + ((u >> 16) & 1u)) >> 16;   // RNE
    return (unsigned short)r;
}
static __device__ __forceinline__ float bf_lo(unsigned d) {
    return __uint_as_float(d << 16);
}
static __device__ __forceinline__ float bf_hi(unsigned d) {
    return __uint_as_float(d & 0xffff0000u);
}

// ---------------------------------------------------------------- utilities

__global__ __launch_bounds__(1024) void zero_int_kernel(int* __restrict__ p, int n) {
    int i = blockIdx.x * 1024 + threadIdx.x;
    if (i < n) p[i] = 0;
}

// W1 fp32 [256 k][128 c]  ->  W1t bf16 [128 c][256 k]
__global__ __launch_bounds__(256) void precast_w1_kernel(const float* __restrict__ W1,
                                                         unsigned short* __restrict__ W1t) {
    int o = blockIdx.x * 256 + threadIdx.x;
    int c = o >> 8, k = o & 255;
    W1t[o] = f2bf(W1[(size_t)k * NHID + c]);
}

// ---------------------------------------------------------------- GEMM1 (MFMA bf16)
__global__ __launch_bounds__(256) void gemm1_mfma_kernel(
    const float* __restrict__ x, const unsigned short* __restrict__ W1t,
    const float* __restrict__ b1, unsigned short* __restrict__ h1b, int N)
{
    __shared__ unsigned short wt[128 * 256];   // 64 KB: [c][k], 16B-slot swizzled
    __shared__ unsigned short xs[64 * 64];     // 8 KB:  [r][k], 16B-slot swizzled

    const int tid = threadIdx.x;
    const int lane = tid & 63;
    const int wv = tid >> 6;
    const int row0 = blockIdx.x * 64;
    const int l15 = lane & 15;
    const int l47 = lane >> 4;
    const int r7 = lane & 7;

    {
        const int4v* src = (const int4v*)W1t;
#pragma unroll
        for (int j = 0; j < 16; ++j) {
            int si = tid + j * 256;
            int c = si >> 5, s = si & 31;
            int sp = (s & 24) | ((s & 7) ^ (c & 7));
            int4v v = src[si];
            *(int4v*)&wt[c * 256 + sp * 8] = v;
        }
    }

    auto stage_x = [&](int t) {
#pragma unroll
        for (int j = 0; j < 2; ++j) {
            int si = tid + j * 256;
            int r = si >> 3, s = si & 7;
            int row = row0 + r;
            float4 v0 = make_float4(0.f, 0.f, 0.f, 0.f), v1 = v0;
            if (row < N) {
                const float4* xp = (const float4*)&x[(size_t)row * NFEAT + t * 64 + s * 8];
                v0 = xp[0]; v1 = xp[1];
            }
            int w0 = f2bf(v0.x) | ((unsigned)f2bf(v0.y) << 16);
            int w1 = f2bf(v0.z) | ((unsigned)f2bf(v0.w) << 16);
            int w2 = f2bf(v1.x) | ((unsigned)f2bf(v1.y) << 16);
            int w3 = f2bf(v1.z) | ((unsigned)f2bf(v1.w) << 16);
            int sp = s ^ (r & 7);
            int4v pv; pv[0] = w0; pv[1] = w1; pv[2] = w2; pv[3] = w3;
            *(int4v*)&xs[r * 64 + sp * 8] = pv;
        }
    };

    f32x4 acc[8];
#pragma unroll
    for (int cf = 0; cf < 8; ++cf)
#pragma unroll
        for (int r = 0; r < 4; ++r) acc[cf][r] = 0.f;

    stage_x(0);
    __syncthreads();

    const int arow = wv * 16 + l15;
#pragma unroll
    for (int t = 0; t < 4; ++t) {
        short8 af[2];
#pragma unroll
        for (int kf = 0; kf < 2; ++kf) {
            int slot = (kf * 4 + l47) ^ r7;
            af[kf] = *(const short8*)&xs[arow * 64 + slot * 8];
        }
#pragma unroll
        for (int cf = 0; cf < 8; ++cf) {
            const int brow = cf * 16 + l15;
#pragma unroll
            for (int kf = 0; kf < 2; ++kf) {
                int slot = t * 8 + ((kf * 4 + l47) ^ r7);
                short8 bfr = *(const short8*)&wt[brow * 256 + slot * 8];
                acc[cf] = __builtin_amdgcn_mfma_f32_16x16x32_bf16(af[kf], bfr, acc[cf], 0, 0, 0);
            }
        }
        __syncthreads();
        if (t < 3) {
            stage_x(t + 1);
            __syncthreads();
        }
    }

#pragma unroll
    for (int cf = 0; cf < 8; ++cf) {
        float bias = b1[cf * 16 + l15];
#pragma unroll
        for (int r = 0; r < 4; ++r) {
            int row = row0 + wv * 16 + l47 * 4 + r;
            if (row < N)
                h1b[(size_t)row * NHID + cf * 16 + l15] = f2bf(acc[cf][r] + bias);
        }
    }
}

// ---------------------------------------------------------------- CSR build (bucketed)
// bucket b = dst >> shift; NBKT <= 256; record = (src | dstlo<<24, bits(w))

__global__ __launch_bounds__(256) void bucket_hist_kernel(const int* __restrict__ dst,
                                                          int* __restrict__ bkt_counts,
                                                          int E, int shift) {
    __shared__ int h[256];
    h[threadIdx.x] = 0;
    __syncthreads();
    for (int e = blockIdx.x * 256 + threadIdx.x; e < E; e += gridDim.x * 256)
        atomicAdd(&h[dst[e] >> shift], 1);
    __syncthreads();
    int v = h[threadIdx.x];
    if (v) atomicAdd(&bkt_counts[threadIdx.x], v);
}

// 1 block: exclusive scan of 256 bucket counts -> bkt_base[257], bkt_cursor
__global__ __launch_bounds__(256) void bucket_scan_kernel(const int* __restrict__ bkt_counts,
                                                          int* __restrict__ bkt_base,
                                                          int* __restrict__ bkt_cursor) {
    __shared__ int s[256];
    int t = threadIdx.x;
    int v = bkt_counts[t];
    s[t] = v;
    __syncthreads();
    for (int off = 1; off < 256; off <<= 1) {
        int tv = (t >= off) ? s[t - off] : 0;
        __syncthreads();
        s[t] += tv;
        __syncthreads();
    }
    int excl = s[t] - v;
    bkt_base[t] = excl;
    bkt_cursor[t] = excl;
    if (t == 255) bkt_base[256] = s[255];
}

// block-aggregated scatter into bucket regions; EPT edges/thread
#define SC_EPT 16
__global__ __launch_bounds__(256) void bucket_scatter_kernel(
    const int* __restrict__ src, const int* __restrict__ dst,
    const float* __restrict__ w, int* __restrict__ bkt_cursor,
    uint2* __restrict__ bkt_edges, int E, int shift)
{
    __shared__ int h[256];
    __shared__ int base[256];
    const int tid = threadIdx.x;
    const int e0 = blockIdx.x * (256 * SC_EPT);
    h[tid] = 0;
    __syncthreads();
#pragma unroll
    for (int j = 0; j < SC_EPT; ++j) {
        int e = e0 + tid + j * 256;
        if (e < E) atomicAdd(&h[dst[e] >> shift], 1);
    }
    __syncthreads();
    int c = h[tid];
    base[tid] = c ? atomicAdd(&bkt_cursor[tid], c) : 0;
    __syncthreads();
    h[tid] = 0;
    __syncthreads();
#pragma unroll
    for (int j = 0; j < SC_EPT; ++j) {
        int e = e0 + tid + j * 256;
        if (e < E) {
            int d = dst[e];
            int b = d >> shift;
            int lp = atomicAdd(&h[b], 1);
            uint2 rec;
            rec.x = (unsigned)src[e] | ((unsigned)(d & ((1 << shift) - 1)) << 24);
            rec.y = __float_as_uint(w[e]);
            bkt_edges[base[b] + lp] = rec;
        }
    }
}

// row-count hist (unchanged, for row_ptr)
__global__ __launch_bounds__(256) void hist_kernel(const int* __restrict__ dst,
                                                   int* __restrict__ counts, int E) {
    int e = blockIdx.x * 256 + threadIdx.x;
    if (e < E) atomicAdd(&counts[dst[e]], 1);
}

__global__ __launch_bounds__(256) void scan_partial_kernel(const int* __restrict__ counts,
                                                           int* __restrict__ partial, int N) {
    __shared__ int s[256];
    int i = blockIdx.x * 256 + threadIdx.x;
    int v = (i < N) ? counts[i] : 0;
    s[threadIdx.x] = v;
    __syncthreads();
    for (int off = 128; off > 0; off >>= 1) {
        if (threadIdx.x < off) s[threadIdx.x] += s[threadIdx.x + off];
        __syncthreads();
    }
    if (threadIdx.x == 0) partial[blockIdx.x] = s[0];
}

__global__ __launch_bounds__(256) void scan_chunk_kernel(const int* __restrict__ partial,
                                                         int* __restrict__ chunk_off,
                                                         int nchunks,
                                                         int* __restrict__ row_ptr, int N) {
    __shared__ int s[256];
    int t = threadIdx.x;
    int v = (t < nchunks) ? partial[t] : 0;
    s[t] = v;
    __syncthreads();
    for (int off = 1; off < 256; off <<= 1) {
        int tv = (t >= off) ? s[t - off] : 0;
        __syncthreads();
        s[t] += tv;
        __syncthreads();
    }
    if (t < nchunks) chunk_off[t] = s[t] - v;
    if (t == 255) row_ptr[N] = s[255];
}

__global__ __launch_bounds__(256) void scan_final_kernel(const int* __restrict__ counts,
                                                         const int* __restrict__ chunk_off,
                                                         int* __restrict__ row_ptr,
                                                         int* __restrict__ cursor, int N) {
    __shared__ int s[256];
    int t = threadIdx.x;
    int i = blockIdx.x * 256 + t;
    int v = (i < N) ? counts[i] : 0;
    s[t] = v;
    __syncthreads();
    for (int off = 1; off < 256; off <<= 1) {
        int tv = (t >= off) ? s[t - off] : 0;
        __syncthreads();
        s[t] += tv;
        __syncthreads();
    }
    if (i < N) {
        int excl = chunk_off[blockIdx.x] + s[t] - v;
        row_ptr[i] = excl;
        cursor[i] = excl;
    }
}

// one block per bucket: bucket records -> final packed CSR (src, w)
__global__ __launch_bounds__(256) void fine_scatter_kernel(
    const int* __restrict__ bkt_base, const uint2* __restrict__ bkt_edges,
    int* __restrict__ cursor, uint2* __restrict__ csr_e, int shift)
{
    const int b = blockIdx.x;
    const int lo = bkt_base[b], hi = bkt_base[b + 1];
    const int dbase = b << shift;
    for (int i = lo + threadIdx.x; i < hi; i += 256) {
        uint2 rec = bkt_edges[i];
        int d = dbase | (int)(rec.x >> 24);
        int pos = atomicAdd(&cursor[d], 1);
        uint2 o;
        o.x = rec.x & 0xFFFFFFu;
        o.y = rec.y;
        csr_e[pos] = o;
    }
}

// ---------------------------------------------------------------- SpMM1 + ReLU
__global__ __launch_bounds__(256) void spmm1_relu_kernel(
    const int* __restrict__ row_ptr, const uint2* __restrict__ csr_e,
    const unsigned short* __restrict__ h1b, float* __restrict__ h1s, int N)
{
    const int lane = threadIdx.x & 63;
    const int wid = threadIdx.x >> 6;
    const int row = blockIdx.x * 4 + wid;
    if (row >= N) return;
    const int e0 = row_ptr[row], e1 = row_ptr[row + 1];
    const size_t loff = (size_t)(lane * 2);
    float a0 = 0.f, a1 = 0.f;
    int e = e0;
    for (; e + 4 <= e1; e += 4) {
        uint2 r0 = csr_e[e], r1 = csr_e[e + 1], r2 = csr_e[e + 2], r3 = csr_e[e + 3];
        float w0 = __uint_as_float(r0.y), w1 = __uint_as_float(r1.y);
        float w2 = __uint_as_float(r2.y), w3 = __uint_as_float(r3.y);
        unsigned d0 = *(const unsigned*)(h1b + (size_t)r0.x * NHID + loff);
        unsigned d1 = *(const unsigned*)(h1b + (size_t)r1.x * NHID + loff);
        unsigned d2 = *(const unsigned*)(h1b + (size_t)r2.x * NHID + loff);
        unsigned d3 = *(const unsigned*)(h1b + (size_t)r3.x * NHID + loff);
        a0 += w0 * bf_lo(d0); a1 += w0 * bf_hi(d0);
        a0 += w1 * bf_lo(d1); a1 += w1 * bf_hi(d1);
        a0 += w2 * bf_lo(d2); a1 += w2 * bf_hi(d2);
        a0 += w3 * bf_lo(d3); a1 += w3 * bf_hi(d3);
    }
    for (; e < e1; ++e) {
        uint2 r = csr_e[e];
        float w = __uint_as_float(r.y);
        unsigned d = *(const unsigned*)(h1b + (size_t)r.x * NHID + loff);
        a0 += w * bf_lo(d); a1 += w * bf_hi(d);
    }
    float2 o = make_float2(fmaxf(a0, 0.f), fmaxf(a1, 0.f));
    *(float2*)&h1s[(size_t)row * NHID + lane * 2] = o;
}

// ---------------------------------------------------------------- GEMM2
__global__ __launch_bounds__(256) void gemm2_kernel(
    const float* __restrict__ h1s, const float* __restrict__ W2,
    const float* __restrict__ b2, float* __restrict__ h2, int N)
{
    __shared__ float hs[32][132];
    __shared__ float w2s[NHID * NCLASS];
    const int tid = threadIdx.x;
#pragma unroll
    for (int j = 0; j < 16; ++j) {
        int idx = tid + j * 256;
        w2s[idx] = W2[idx];
    }
    const int row0 = blockIdx.x * 32;
#pragma unroll
    for (int j = 0; j < 4; ++j) {
        int idx = tid + j * 256;
        int r = idx >> 5, c4 = idx & 31;
        int row = row0 + r;
        float4 v = (row < N) ? *(const float4*)&h1s[(size_t)row * NHID + c4 * 4]
                             : make_float4(0.f, 0.f, 0.f, 0.f);
        *(float4*)&hs[r][c4 * 4] = v;
    }
    __syncthreads();

    const int rl = tid >> 3;
    const int cgp = tid & 7;
    float4 bv = *(const float4*)&b2[cgp * 4];
    float acc[4] = {bv.x, bv.y, bv.z, bv.w};
#pragma unroll
    for (int k = 0; k < NHID; k += 4) {
        float4 hv = *(const float4*)&hs[rl][k];
        float hf[4] = {hv.x, hv.y, hv.z, hv.w};
#pragma unroll
        for (int q = 0; q < 4; ++q) {
            float4 wv = *(const float4*)&w2s[(k + q) * NCLASS + cgp * 4];
            acc[0] += hf[q] * wv.x;
            acc[1] += hf[q] * wv.y;
            acc[2] += hf[q] * wv.z;
            acc[3] += hf[q] * wv.w;
        }
    }
    int row = row0 + rl;
    if (row < N)
        *(float4*)&h2[(size_t)row * NCLASS + cgp * 4] =
            make_float4(acc[0], acc[1], acc[2], acc[3]);
}

// ---------------------------------------------------------------- SpMM2
__global__ __launch_bounds__(256) void spmm2_kernel(
    const int* __restrict__ row_ptr, const uint2* __restrict__ csr_e,
    const float* __restrict__ h2, float* __restrict__ out, int N)
{
    const int c = threadIdx.x & 31;
    const int rl = threadIdx.x >> 5;
    const int row = blockIdx.x * 8 + rl;
    if (row >= N) return;
    const int e0 = row_ptr[row], e1 = row_ptr[row + 1];
    float a = 0.f;
    int e = e0;
    for (; e + 4 <= e1; e += 4) {
        uint2 r0 = csr_e[e], r1 = csr_e[e + 1], r2 = csr_e[e + 2], r3 = csr_e[e + 3];
        float v0 = h2[(size_t)r0.x * NCLASS + c];
        float v1 = h2[(size_t)r1.x * NCLASS + c];
        float v2 = h2[(size_t)r2.x * NCLASS + c];
        float v3 = h2[(size_t)r3.x * NCLASS + c];
        a += __uint_as_float(r0.y) * v0 + __uint_as_float(r1.y) * v1
           + __uint_as_float(r2.y) * v2 + __uint_as_float(r3.y) * v3;
    }
    for (; e < e1; ++e) {
        uint2 r = csr_e[e];
        a += __uint_as_float(r.y) * h2[(size_t)r.x * NCLASS + c];
    }
    out[(size_t)row * NCLASS + c] = a;
}

// ---------------------------------------------------------------- launch

extern "C" void kernel_launch(void* const* d_in, const int* in_sizes, int n_in,
                              void* d_out, int out_size, void* d_ws, size_t ws_size,
                              hipStream_t stream) {
    const float* x    = (const float*)d_in[0];
    const int*   esrc = (const int*)d_in[1];
    const int*   edst = (const int*)d_in[2];
    const float* ew   = (const float*)d_in[3];
    const float* W1   = (const float*)d_in[4];
    const float* b1   = (const float*)d_in[5];
    const float* W2   = (const float*)d_in[6];
    const float* b2   = (const float*)d_in[7];
    float* out = (float*)d_out;

    const int N = in_sizes[0] / NFEAT;
    const int E = in_sizes[1];

    // coarse bucket shift: smallest s with ((N-1)>>s) < 256 (N<=65536 -> s<=8)
    int shift = 0;
    while (((N - 1) >> shift) >= 256) ++shift;
    const int NBKT = ((N - 1) >> shift) + 1;

    char* base = (char*)d_ws;
    size_t off = 0;
    auto take = [&](size_t bytes) -> void* {
        void* p = base + off;
        off += (bytes + 255) & ~(size_t)255;
        return p;
    };
    unsigned short* h1b = (unsigned short*)take((size_t)N * NHID * sizeof(unsigned short));
    float* h1s     = (float*)take((size_t)N * NHID * sizeof(float));
    float* h2      = (float*)take((size_t)N * NCLASS * sizeof(float));
    int*   row_ptr = (int*)take((size_t)(N + 1) * sizeof(int));
    int*   cursor  = (int*)take((size_t)N * sizeof(int));
    int*   counts  = (int*)take((size_t)N * sizeof(int));
    int*   partial = (int*)take(256 * sizeof(int));
    int*   chunkoff= (int*)take(256 * sizeof(int));
    int*   bkt_counts = (int*)take(256 * sizeof(int));
    int*   bkt_base   = (int*)take(257 * sizeof(int));
    int*   bkt_cursor = (int*)take(256 * sizeof(int));
    uint2* bkt_edges  = (uint2*)take((size_t)E * sizeof(uint2));
    uint2* csr_e      = (uint2*)take((size_t)E * sizeof(uint2));
    unsigned short* W1t = (unsigned short*)take((size_t)NFEAT * NHID * sizeof(unsigned short));
    (void)ws_size; (void)n_in; (void)out_size;

    const int nchunks = (N + 255) / 256;

    zero_int_kernel<<<(N + 1023) / 1024, 1024, 0, stream>>>(counts, N);
    zero_int_kernel<<<1, 1024, 0, stream>>>(bkt_counts, 256);
    precast_w1_kernel<<<(NFEAT * NHID) / 256, 256, 0, stream>>>(W1, W1t);
    gemm1_mfma_kernel<<<(N + 63) / 64, 256, 0, stream>>>(x, W1t, b1, h1b, N);

    bucket_hist_kernel<<<256, 256, 0, stream>>>(edst, bkt_counts, E, shift);
    bucket_scan_kernel<<<1, 256, 0, stream>>>(bkt_counts, bkt_base, bkt_cursor);
    hist_kernel<<<(E + 255) / 256, 256, 0, stream>>>(edst, counts, E);
    scan_partial_kernel<<<nchunks, 256, 0, stream>>>(counts, partial, N);
    scan_chunk_kernel<<<1, 256, 0, stream>>>(partial, chunkoff, nchunks, row_ptr, N);
    scan_final_kernel<<<nchunks, 256, 0, stream>>>(counts, chunkoff, row_ptr, cursor, N);
    bucket_scatter_kernel<<<(E + 256 * SC_EPT - 1) / (256 * SC_EPT), 256, 0, stream>>>(
        esrc, edst, ew, bkt_cursor, bkt_edges, E, shift);
    fine_scatter_kernel<<<NBKT, 256, 0, stream>>>(bkt_base, bkt_edges, cursor, csr_e, shift);

    spmm1_relu_kernel<<<(N + 3) / 4, 256, 0, stream>>>(row_ptr, csr_e, h1b, h1s, N);
    gemm2_kernel<<<(N + 31) / 32, 256, 0, stream>>>(h1s, W2, b2, h2, N);
    spmm2_kernel<<<(N + 7) / 8, 256, 0, stream>>>(row_ptr, csr_e, h2, out, N);
}

// Round 5
// 142.485 us; speedup vs baseline: 2.1192x; 1.4019x over previous
//
#include <hip/hip_runtime.h>

#define NFEAT 256
#define NHID 128
#define NCLASS 32

typedef __attribute__((ext_vector_type(8))) short short8;
typedef __attribute__((ext_vector_type(4))) float f32x4;
typedef __attribute__((ext_vector_type(4))) int int4v;

static __device__ __forceinline__ unsigned short f2bf(float f) {
    unsigned u = __float_as_uint(f);
    unsigned r = (u + 0x7fffu + ((u >> 16) & 1u)) >> 16;   // RNE
    return (unsigned short)r;
}
static __device__ __forceinline__ float bf_lo(unsigned d) {
    return __uint_as_float(d << 16);
}
static __device__ __forceinline__ float bf_hi(unsigned d) {
    return __uint_as_float(d & 0xffff0000u);
}

// ---------------------------------------------------------------- prep:
// blocks 0..127   : precast W1 fp32 [256k][128c] -> W1t bf16 [128c][256k]
// blocks 128..383 : private bucket histogram -> bkt_partial[kb][256]
__global__ __launch_bounds__(256) void prep_kernel(
    const float* __restrict__ W1, unsigned short* __restrict__ W1t,
    const int* __restrict__ dst, int* __restrict__ bkt_partial, int E, int shift)
{
    const int tid = threadIdx.x;
    if (blockIdx.x < 128) {
        int o = blockIdx.x * 256 + tid;            // 32768 outputs
        int c = o >> 8, k = o & 255;
        W1t[o] = f2bf(W1[(size_t)k * NHID + c]);
    } else {
        __shared__ int h[256];
        const int kb = blockIdx.x - 128;           // 0..255
        h[tid] = 0;
        __syncthreads();
        for (int e = kb * 256 + tid; e < E; e += 256 * 256)
            atomicAdd(&h[dst[e] >> shift], 1);
        __syncthreads();
        bkt_partial[kb * 256 + tid] = h[tid];
    }
}

// ---------------------------------------------------------------- GEMM1 (MFMA bf16)
__global__ __launch_bounds__(256) void gemm1_mfma_kernel(
    const float* __restrict__ x, const unsigned short* __restrict__ W1t,
    const float* __restrict__ b1, unsigned short* __restrict__ h1b, int N)
{
    __shared__ unsigned short wt[128 * 256];   // 64 KB: [c][k], 16B-slot swizzled
    __shared__ unsigned short xs[64 * 64];     // 8 KB:  [r][k], 16B-slot swizzled

    const int tid = threadIdx.x;
    const int lane = tid & 63;
    const int wv = tid >> 6;
    const int row0 = blockIdx.x * 64;
    const int l15 = lane & 15;
    const int l47 = lane >> 4;
    const int r7 = lane & 7;

    {
        const int4v* src = (const int4v*)W1t;
#pragma unroll
        for (int j = 0; j < 16; ++j) {
            int si = tid + j * 256;
            int c = si >> 5, s = si & 31;
            int sp = (s & 24) | ((s & 7) ^ (c & 7));
            int4v v = src[si];
            *(int4v*)&wt[c * 256 + sp * 8] = v;
        }
    }

    auto stage_x = [&](int t) {
#pragma unroll
        for (int j = 0; j < 2; ++j) {
            int si = tid + j * 256;
            int r = si >> 3, s = si & 7;
            int row = row0 + r;
            float4 v0 = make_float4(0.f, 0.f, 0.f, 0.f), v1 = v0;
            if (row < N) {
                const float4* xp = (const float4*)&x[(size_t)row * NFEAT + t * 64 + s * 8];
                v0 = xp[0]; v1 = xp[1];
            }
            int w0 = f2bf(v0.x) | ((unsigned)f2bf(v0.y) << 16);
            int w1 = f2bf(v0.z) | ((unsigned)f2bf(v0.w) << 16);
            int w2 = f2bf(v1.x) | ((unsigned)f2bf(v1.y) << 16);
            int w3 = f2bf(v1.z) | ((unsigned)f2bf(v1.w) << 16);
            int sp = s ^ (r & 7);
            int4v pv; pv[0] = w0; pv[1] = w1; pv[2] = w2; pv[3] = w3;
            *(int4v*)&xs[r * 64 + sp * 8] = pv;
        }
    };

    f32x4 acc[8];
#pragma unroll
    for (int cf = 0; cf < 8; ++cf)
#pragma unroll
        for (int r = 0; r < 4; ++r) acc[cf][r] = 0.f;

    stage_x(0);
    __syncthreads();

    const int arow = wv * 16 + l15;
#pragma unroll
    for (int t = 0; t < 4; ++t) {
        short8 af[2];
#pragma unroll
        for (int kf = 0; kf < 2; ++kf) {
            int slot = (kf * 4 + l47) ^ r7;
            af[kf] = *(const short8*)&xs[arow * 64 + slot * 8];
        }
#pragma unroll
        for (int cf = 0; cf < 8; ++cf) {
            const int brow = cf * 16 + l15;
#pragma unroll
            for (int kf = 0; kf < 2; ++kf) {
                int slot = t * 8 + ((kf * 4 + l47) ^ r7);
                short8 bfr = *(const short8*)&wt[brow * 256 + slot * 8];
                acc[cf] = __builtin_amdgcn_mfma_f32_16x16x32_bf16(af[kf], bfr, acc[cf], 0, 0, 0);
            }
        }
        __syncthreads();
        if (t < 3) {
            stage_x(t + 1);
            __syncthreads();
        }
    }

#pragma unroll
    for (int cf = 0; cf < 8; ++cf) {
        float bias = b1[cf * 16 + l15];
#pragma unroll
        for (int r = 0; r < 4; ++r) {
            int row = row0 + wv * 16 + l47 * 4 + r;
            if (row < N)
                h1b[(size_t)row * NHID + cf * 16 + l15] = f2bf(acc[cf][r] + bias);
        }
    }
}

// ---------------------------------------------------------------- bucket scan
// 1 block: reduce bkt_partial[256][256] along k, exclusive-scan -> base/cursor
__global__ __launch_bounds__(256) void bucket_scan_kernel(
    const int* __restrict__ bkt_partial, int* __restrict__ bkt_base,
    int* __restrict__ bkt_cursor)
{
    __shared__ int s[256];
    const int t = threadIdx.x;
    int v = 0;
    for (int k = 0; k < 256; ++k) v += bkt_partial[k * 256 + t];
    s[t] = v;
    __syncthreads();
    for (int off = 1; off < 256; off <<= 1) {
        int tv = (t >= off) ? s[t - off] : 0;
        __syncthreads();
        s[t] += tv;
        __syncthreads();
    }
    int excl = s[t] - v;
    bkt_base[t] = excl;
    bkt_cursor[t] = excl;
    if (t == 255) bkt_base[256] = s[255];
}

// ---------------------------------------------------------------- bucket scatter
#define SC_EPT 16
__global__ __launch_bounds__(256) void bucket_scatter_kernel(
    const int* __restrict__ src, const int* __restrict__ dst,
    const float* __restrict__ w, int* __restrict__ bkt_cursor,
    uint2* __restrict__ bkt_edges, int E, int shift)
{
    __shared__ int h[256];
    __shared__ int base[256];
    const int tid = threadIdx.x;
    const int e0 = blockIdx.x * (256 * SC_EPT);
    h[tid] = 0;
    __syncthreads();
#pragma unroll
    for (int j = 0; j < SC_EPT; ++j) {
        int e = e0 + tid + j * 256;
        if (e < E) atomicAdd(&h[dst[e] >> shift], 1);
    }
    __syncthreads();
    int c = h[tid];
    base[tid] = c ? atomicAdd(&bkt_cursor[tid], c) : 0;
    __syncthreads();
    h[tid] = 0;
    __syncthreads();
#pragma unroll
    for (int j = 0; j < SC_EPT; ++j) {
        int e = e0 + tid + j * 256;
        if (e < E) {
            int d = dst[e];
            int b = d >> shift;
            int lp = atomicAdd(&h[b], 1);
            uint2 rec;
            rec.x = (unsigned)src[e] | ((unsigned)(d & ((1 << shift) - 1)) << 24);
            rec.y = __float_as_uint(w[e]);
            bkt_edges[base[b] + lp] = rec;
        }
    }
}

// ---------------------------------------------------------------- fine scatter + row_ptr
// one block per bucket: local row hist -> scan -> row_ptr write + packed CSR
__global__ __launch_bounds__(256) void fine_scatter_kernel(
    const int* __restrict__ bkt_base, const uint2* __restrict__ bkt_edges,
    int* __restrict__ row_ptr, uint2* __restrict__ csr_e,
    int shift, int N, int E)
{
    __shared__ int h[256];
    __shared__ int cur[256];
    const int b = blockIdx.x;
    const int t = threadIdx.x;
    const int lo = bkt_base[b], hi = bkt_base[b + 1];
    const int dbase = b << shift;

    h[t] = 0;
    __syncthreads();
    for (int i = lo + t; i < hi; i += 256)
        atomicAdd(&h[bkt_edges[i].x >> 24], 1);
    __syncthreads();
    int v = h[t];
    __syncthreads();
    h[t] = v;
    __syncthreads();
    for (int off = 1; off < 256; off <<= 1) {
        int tv = (t >= off) ? h[t - off] : 0;
        __syncthreads();
        h[t] += tv;
        __syncthreads();
    }
    int excl = h[t] - v;
    {
        int r = dbase + t;
        if (r < N) row_ptr[r] = lo + excl;
    }
    if (b == 0 && t == 0) row_ptr[N] = E;
    cur[t] = lo + excl;
    __syncthreads();
    for (int i = lo + t; i < hi; i += 256) {
        uint2 rec = bkt_edges[i];
        int dl = rec.x >> 24;
        int pos = atomicAdd(&cur[dl], 1);
        uint2 o;
        o.x = rec.x & 0xFFFFFFu;
        o.y = rec.y;
        csr_e[pos] = o;
    }
}

// ---------------------------------------------------------------- SpMM1 + ReLU + GEMM2
// per wave: h2[row] = (relu(sum_e w_e * h1b[src_e])) @ W2 + b2
__global__ __launch_bounds__(256) void spmm1_gemm2_kernel(
    const int* __restrict__ row_ptr, const uint2* __restrict__ csr_e,
    const unsigned short* __restrict__ h1b, const float* __restrict__ W2,
    const float* __restrict__ b2, float* __restrict__ h2, int N)
{
    __shared__ float w2s[NHID * NCLASS];   // 16 KB, [k][c]
    __shared__ float hrow[4][NHID];        // per-wave row strip
    const int tid = threadIdx.x;
#pragma unroll
    for (int j = 0; j < 16; ++j) {
        int idx = tid + j * 256;
        w2s[idx] = W2[idx];
    }
    __syncthreads();

    const int lane = tid & 63;
    const int wv = tid >> 6;
    const int row = blockIdx.x * 4 + wv;
    if (row >= N) return;

    const int e0 = row_ptr[row], e1 = row_ptr[row + 1];
    const size_t loff = (size_t)(lane * 2);
    float a0 = 0.f, a1 = 0.f;
    int e = e0;
    for (; e + 4 <= e1; e += 4) {
        uint2 r0 = csr_e[e], r1 = csr_e[e + 1], r2 = csr_e[e + 2], r3 = csr_e[e + 3];
        float w0 = __uint_as_float(r0.y), w1 = __uint_as_float(r1.y);
        float w2 = __uint_as_float(r2.y), w3 = __uint_as_float(r3.y);
        unsigned d0 = *(const unsigned*)(h1b + (size_t)r0.x * NHID + loff);
        unsigned d1 = *(const unsigned*)(h1b + (size_t)r1.x * NHID + loff);
        unsigned d2 = *(const unsigned*)(h1b + (size_t)r2.x * NHID + loff);
        unsigned d3 = *(const unsigned*)(h1b + (size_t)r3.x * NHID + loff);
        a0 += w0 * bf_lo(d0); a1 += w0 * bf_hi(d0);
        a0 += w1 * bf_lo(d1); a1 += w1 * bf_hi(d1);
        a0 += w2 * bf_lo(d2); a1 += w2 * bf_hi(d2);
        a0 += w3 * bf_lo(d3); a1 += w3 * bf_hi(d3);
    }
    for (; e < e1; ++e) {
        uint2 r = csr_e[e];
        float w = __uint_as_float(r.y);
        unsigned d = *(const unsigned*)(h1b + (size_t)r.x * NHID + loff);
        a0 += w * bf_lo(d); a1 += w * bf_hi(d);
    }
    // relu'd row strip -> LDS (wave-local; no block barrier needed)
    *(float2*)&hrow[wv][lane * 2] = make_float2(fmaxf(a0, 0.f), fmaxf(a1, 0.f));

    // in-wave gemm2: half-wave split over k, lanes 0..31 own output cols
    const int c = lane & 31;
    const int half = lane >> 5;
    const float* hw = &hrow[wv][half * 64];
    const float* wp = &w2s[(size_t)half * 64 * NCLASS + c];
    float acc = 0.f;
#pragma unroll
    for (int k = 0; k < 64; ++k)
        acc += hw[k] * wp[k * NCLASS];
    acc += __shfl(acc, lane ^ 32);
    if (half == 0)
        h2[(size_t)row * NCLASS + c] = acc + b2[c];
}

// ---------------------------------------------------------------- SpMM2
__global__ __launch_bounds__(256) void spmm2_kernel(
    const int* __restrict__ row_ptr, const uint2* __restrict__ csr_e,
    const float* __restrict__ h2, float* __restrict__ out, int N)
{
    const int c = threadIdx.x & 31;
    const int rl = threadIdx.x >> 5;
    const int row = blockIdx.x * 8 + rl;
    if (row >= N) return;
    const int e0 = row_ptr[row], e1 = row_ptr[row + 1];
    float a = 0.f;
    int e = e0;
    for (; e + 4 <= e1; e += 4) {
        uint2 r0 = csr_e[e], r1 = csr_e[e + 1], r2 = csr_e[e + 2], r3 = csr_e[e + 3];
        float v0 = h2[(size_t)r0.x * NCLASS + c];
        float v1 = h2[(size_t)r1.x * NCLASS + c];
        float v2 = h2[(size_t)r2.x * NCLASS + c];
        float v3 = h2[(size_t)r3.x * NCLASS + c];
        a += __uint_as_float(r0.y) * v0 + __uint_as_float(r1.y) * v1
           + __uint_as_float(r2.y) * v2 + __uint_as_float(r3.y) * v3;
    }
    for (; e < e1; ++e) {
        uint2 r = csr_e[e];
        a += __uint_as_float(r.y) * h2[(size_t)r.x * NCLASS + c];
    }
    out[(size_t)row * NCLASS + c] = a;
}

// ---------------------------------------------------------------- launch

extern "C" void kernel_launch(void* const* d_in, const int* in_sizes, int n_in,
                              void* d_out, int out_size, void* d_ws, size_t ws_size,
                              hipStream_t stream) {
    const float* x    = (const float*)d_in[0];
    const int*   esrc = (const int*)d_in[1];
    const int*   edst = (const int*)d_in[2];
    const float* ew   = (const float*)d_in[3];
    const float* W1   = (const float*)d_in[4];
    const float* b1   = (const float*)d_in[5];
    const float* W2   = (const float*)d_in[6];
    const float* b2   = (const float*)d_in[7];
    float* out = (float*)d_out;

    const int N = in_sizes[0] / NFEAT;
    const int E = in_sizes[1];

    // coarse bucket shift: smallest s with ((N-1)>>s) < 256
    int shift = 0;
    while (((N - 1) >> shift) >= 256) ++shift;
    const int NBKT = ((N - 1) >> shift) + 1;

    char* base = (char*)d_ws;
    size_t off = 0;
    auto take = [&](size_t bytes) -> void* {
        void* p = base + off;
        off += (bytes + 255) & ~(size_t)255;
        return p;
    };
    unsigned short* h1b = (unsigned short*)take((size_t)N * NHID * sizeof(unsigned short));
    float* h2      = (float*)take((size_t)N * NCLASS * sizeof(float));
    int*   row_ptr = (int*)take((size_t)(N + 1) * sizeof(int));
    int*   bkt_partial = (int*)take(256 * 256 * sizeof(int));
    int*   bkt_base    = (int*)take(257 * sizeof(int));
    int*   bkt_cursor  = (int*)take(256 * sizeof(int));
    uint2* bkt_edges   = (uint2*)take((size_t)E * sizeof(uint2));
    uint2* csr_e       = (uint2*)take((size_t)E * sizeof(uint2));
    unsigned short* W1t = (unsigned short*)take((size_t)NFEAT * NHID * sizeof(unsigned short));
    (void)ws_size; (void)n_in; (void)out_size;

    prep_kernel<<<384, 256, 0, stream>>>(W1, W1t, edst, bkt_partial, E, shift);
    gemm1_mfma_kernel<<<(N + 63) / 64, 256, 0, stream>>>(x, W1t, b1, h1b, N);
    bucket_scan_kernel<<<1, 256, 0, stream>>>(bkt_partial, bkt_base, bkt_cursor);
    bucket_scatter_kernel<<<(E + 256 * SC_EPT - 1) / (256 * SC_EPT), 256, 0, stream>>>(
        esrc, edst, ew, bkt_cursor, bkt_edges, E, shift);
    fine_scatter_kernel<<<NBKT, 256, 0, stream>>>(bkt_base, bkt_edges, row_ptr, csr_e,
                                                  shift, N, E);
    spmm1_gemm2_kernel<<<(N + 3) / 4, 256, 0, stream>>>(row_ptr, csr_e, h1b, W2, b2, h2, N);
    spmm2_kernel<<<(N + 7) / 8, 256, 0, stream>>>(row_ptr, csr_e, h2, out, N);
}

// Round 6
// 125.773 us; speedup vs baseline: 2.4008x; 1.1329x over previous
//
#include <hip/hip_runtime.h>

#define NFEAT 256
#define NHID 128
#define NCLASS 32

typedef __attribute__((ext_vector_type(8))) short short8;
typedef __attribute__((ext_vector_type(4))) float f32x4;
typedef __attribute__((ext_vector_type(4))) int int4v;

static __device__ __forceinline__ unsigned short f2bf(float f) {
    unsigned u = __float_as_uint(f);
    unsigned r = (u + 0x7fffu + ((u >> 16) & 1u)) >> 16;   // RNE
    return (unsigned short)r;
}
static __device__ __forceinline__ float bf_lo(unsigned d) {
    return __uint_as_float(d << 16);
}
static __device__ __forceinline__ float bf_hi(unsigned d) {
    return __uint_as_float(d & 0xffff0000u);
}

// ---------------------------------------------------------------- prep:
// blocks 0..127   : precast W1 fp32 [256k][128c] -> W1t bf16 [128c][256k]
// blocks 128..383 : private bucket histogram -> bkt_partial[kb][256]
__global__ __launch_bounds__(256) void prep_kernel(
    const float* __restrict__ W1, unsigned short* __restrict__ W1t,
    const int* __restrict__ dst, int* __restrict__ bkt_partial, int E, int shift)
{
    const int tid = threadIdx.x;
    if (blockIdx.x < 128) {
        int o = blockIdx.x * 256 + tid;
        int c = o >> 8, k = o & 255;
        W1t[o] = f2bf(W1[(size_t)k * NHID + c]);
    } else {
        __shared__ int h[256];
        const int kb = blockIdx.x - 128;
        h[tid] = 0;
        __syncthreads();
        for (int e = kb * 256 + tid; e < E; e += 256 * 256)
            atomicAdd(&h[dst[e] >> shift], 1);
        __syncthreads();
        bkt_partial[kb * 256 + tid] = h[tid];
    }
}

// ---------------------------------------------------------------- GEMM1 (MFMA bf16)
__global__ __launch_bounds__(256) void gemm1_mfma_kernel(
    const float* __restrict__ x, const unsigned short* __restrict__ W1t,
    const float* __restrict__ b1, unsigned short* __restrict__ h1b, int N)
{
    __shared__ unsigned short wt[128 * 256];   // 64 KB: [c][k], 16B-slot swizzled
    __shared__ unsigned short xs[64 * 64];     // 8 KB:  [r][k], 16B-slot swizzled

    const int tid = threadIdx.x;
    const int lane = tid & 63;
    const int wv = tid >> 6;
    const int row0 = blockIdx.x * 64;
    const int l15 = lane & 15;
    const int l47 = lane >> 4;
    const int r7 = lane & 7;

    {
        const int4v* src = (const int4v*)W1t;
#pragma unroll
        for (int j = 0; j < 16; ++j) {
            int si = tid + j * 256;
            int c = si >> 5, s = si & 31;
            int sp = (s & 24) | ((s & 7) ^ (c & 7));
            int4v v = src[si];
            *(int4v*)&wt[c * 256 + sp * 8] = v;
        }
    }

    auto stage_x = [&](int t) {
#pragma unroll
        for (int j = 0; j < 2; ++j) {
            int si = tid + j * 256;
            int r = si >> 3, s = si & 7;
            int row = row0 + r;
            float4 v0 = make_float4(0.f, 0.f, 0.f, 0.f), v1 = v0;
            if (row < N) {
                const float4* xp = (const float4*)&x[(size_t)row * NFEAT + t * 64 + s * 8];
                v0 = xp[0]; v1 = xp[1];
            }
            int w0 = f2bf(v0.x) | ((unsigned)f2bf(v0.y) << 16);
            int w1 = f2bf(v0.z) | ((unsigned)f2bf(v0.w) << 16);
            int w2 = f2bf(v1.x) | ((unsigned)f2bf(v1.y) << 16);
            int w3 = f2bf(v1.z) | ((unsigned)f2bf(v1.w) << 16);
            int sp = s ^ (r & 7);
            int4v pv; pv[0] = w0; pv[1] = w1; pv[2] = w2; pv[3] = w3;
            *(int4v*)&xs[r * 64 + sp * 8] = pv;
        }
    };

    f32x4 acc[8];
#pragma unroll
    for (int cf = 0; cf < 8; ++cf)
#pragma unroll
        for (int r = 0; r < 4; ++r) acc[cf][r] = 0.f;

    stage_x(0);
    __syncthreads();

    const int arow = wv * 16 + l15;
#pragma unroll
    for (int t = 0; t < 4; ++t) {
        short8 af[2];
#pragma unroll
        for (int kf = 0; kf < 2; ++kf) {
            int slot = (kf * 4 + l47) ^ r7;
            af[kf] = *(const short8*)&xs[arow * 64 + slot * 8];
        }
#pragma unroll
        for (int cf = 0; cf < 8; ++cf) {
            const int brow = cf * 16 + l15;
#pragma unroll
            for (int kf = 0; kf < 2; ++kf) {
                int slot = t * 8 + ((kf * 4 + l47) ^ r7);
                short8 bfr = *(const short8*)&wt[brow * 256 + slot * 8];
                acc[cf] = __builtin_amdgcn_mfma_f32_16x16x32_bf16(af[kf], bfr, acc[cf], 0, 0, 0);
            }
        }
        __syncthreads();
        if (t < 3) {
            stage_x(t + 1);
            __syncthreads();
        }
    }

#pragma unroll
    for (int cf = 0; cf < 8; ++cf) {
        float bias = b1[cf * 16 + l15];
#pragma unroll
        for (int r = 0; r < 4; ++r) {
            int row = row0 + wv * 16 + l47 * 4 + r;
            if (row < N)
                h1b[(size_t)row * NHID + cf * 16 + l15] = f2bf(acc[cf][r] + bias);
        }
    }
}

// ---------------------------------------------------------------- bucket scan
__global__ __launch_bounds__(256) void bucket_scan_kernel(
    const int* __restrict__ bkt_partial, int* __restrict__ bkt_base,
    int* __restrict__ bkt_cursor)
{
    __shared__ int s[256];
    const int t = threadIdx.x;
    int v = 0;
    for (int k = 0; k < 256; ++k) v += bkt_partial[k * 256 + t];
    s[t] = v;
    __syncthreads();
    for (int off = 1; off < 256; off <<= 1) {
        int tv = (t >= off) ? s[t - off] : 0;
        __syncthreads();
        s[t] += tv;
        __syncthreads();
    }
    int excl = s[t] - v;
    bkt_base[t] = excl;
    bkt_cursor[t] = excl;
    if (t == 255) bkt_base[256] = s[255];
}

// ---------------------------------------------------------------- bucket scatter
#define SC_EPT 16
__global__ __launch_bounds__(256) void bucket_scatter_kernel(
    const int* __restrict__ src, const int* __restrict__ dst,
    const float* __restrict__ w, int* __restrict__ bkt_cursor,
    uint2* __restrict__ bkt_edges, int E, int shift)
{
    __shared__ int h[256];
    __shared__ int base[256];
    const int tid = threadIdx.x;
    const int e0 = blockIdx.x * (256 * SC_EPT);
    h[tid] = 0;
    __syncthreads();
#pragma unroll
    for (int j = 0; j < SC_EPT; ++j) {
        int e = e0 + tid + j * 256;
        if (e < E) atomicAdd(&h[dst[e] >> shift], 1);
    }
    __syncthreads();
    int c = h[tid];
    base[tid] = c ? atomicAdd(&bkt_cursor[tid], c) : 0;
    __syncthreads();
    h[tid] = 0;
    __syncthreads();
#pragma unroll
    for (int j = 0; j < SC_EPT; ++j) {
        int e = e0 + tid + j * 256;
        if (e < E) {
            int d = dst[e];
            int b = d >> shift;
            int lp = atomicAdd(&h[b], 1);
            uint2 rec;
            rec.x = (unsigned)src[e] | ((unsigned)(d & ((1 << shift) - 1)) << 24);
            rec.y = __float_as_uint(w[e]);
            bkt_edges[base[b] + lp] = rec;
        }
    }
}

// ---------------------------------------------------------------- fine scatter + row_ptr
__global__ __launch_bounds__(256) void fine_scatter_kernel(
    const int* __restrict__ bkt_base, const uint2* __restrict__ bkt_edges,
    int* __restrict__ row_ptr, uint2* __restrict__ csr_e,
    int shift, int N, int E)
{
    __shared__ int h[256];
    __shared__ int cur[256];
    const int b = blockIdx.x;
    const int t = threadIdx.x;
    const int lo = bkt_base[b], hi = bkt_base[b + 1];
    const int dbase = b << shift;

    h[t] = 0;
    __syncthreads();
    for (int i = lo + t; i < hi; i += 256)
        atomicAdd(&h[bkt_edges[i].x >> 24], 1);
    __syncthreads();
    int v = h[t];
    __syncthreads();
    h[t] = v;
    __syncthreads();
    for (int off = 1; off < 256; off <<= 1) {
        int tv = (t >= off) ? h[t - off] : 0;
        __syncthreads();
        h[t] += tv;
        __syncthreads();
    }
    int excl = h[t] - v;
    {
        int r = dbase + t;
        if (r < N) row_ptr[r] = lo + excl;
    }
    if (b == 0 && t == 0) row_ptr[N] = E;
    cur[t] = lo + excl;
    __syncthreads();
    for (int i = lo + t; i < hi; i += 256) {
        uint2 rec = bkt_edges[i];
        int dl = rec.x >> 24;
        int pos = atomicAdd(&cur[dl], 1);
        uint2 o;
        o.x = rec.x & 0xFFFFFFu;
        o.y = rec.y;
        csr_e[pos] = o;
    }
}

// ---------------------------------------------------------------- SpMM1 + ReLU + GEMM2
// 512 thr = 8 waves = 8 rows/block. h2b[row][32] bf16 (16 dwords).
__global__ __launch_bounds__(512) void spmm1_gemm2_kernel(
    const int* __restrict__ row_ptr, const uint2* __restrict__ csr_e,
    const unsigned short* __restrict__ h1b, const float* __restrict__ W2,
    const float* __restrict__ b2, unsigned* __restrict__ h2b, int N)
{
    __shared__ float w2s[NHID * NCLASS];   // 16 KB, [k][c]
    __shared__ float hrow[8][NHID];        // per-wave row strip, 4 KB
    const int tid = threadIdx.x;
#pragma unroll
    for (int j = 0; j < 8; ++j) {
        int idx = tid + j * 512;
        w2s[idx] = W2[idx];
    }
    __syncthreads();

    const int lane = tid & 63;
    const int wv = tid >> 6;
    const int row = __builtin_amdgcn_readfirstlane(blockIdx.x * 8 + wv);
    if (row >= N) return;

    const int e0 = row_ptr[row], e1 = row_ptr[row + 1];
    const size_t loff = (size_t)(lane * 2);
    float a0 = 0.f, a1 = 0.f;
    int e = e0;
    for (; e + 8 <= e1; e += 8) {
        uint2 r[8];
#pragma unroll
        for (int j = 0; j < 8; ++j) r[j] = csr_e[e + j];
        unsigned d[8];
#pragma unroll
        for (int j = 0; j < 8; ++j)
            d[j] = *(const unsigned*)(h1b + (size_t)r[j].x * NHID + loff);
#pragma unroll
        for (int j = 0; j < 8; ++j) {
            float w = __uint_as_float(r[j].y);
            a0 += w * bf_lo(d[j]); a1 += w * bf_hi(d[j]);
        }
    }
    for (; e + 2 <= e1; e += 2) {
        uint2 r0 = csr_e[e], r1 = csr_e[e + 1];
        unsigned d0 = *(const unsigned*)(h1b + (size_t)r0.x * NHID + loff);
        unsigned d1 = *(const unsigned*)(h1b + (size_t)r1.x * NHID + loff);
        float w0 = __uint_as_float(r0.y), w1 = __uint_as_float(r1.y);
        a0 += w0 * bf_lo(d0); a1 += w0 * bf_hi(d0);
        a0 += w1 * bf_lo(d1); a1 += w1 * bf_hi(d1);
    }
    if (e < e1) {
        uint2 r = csr_e[e];
        float w = __uint_as_float(r.y);
        unsigned d = *(const unsigned*)(h1b + (size_t)r.x * NHID + loff);
        a0 += w * bf_lo(d); a1 += w * bf_hi(d);
    }
    // relu'd row strip -> LDS (wave-local; no block barrier needed)
    *(float2*)&hrow[wv][lane * 2] = make_float2(fmaxf(a0, 0.f), fmaxf(a1, 0.f));

    // in-wave gemm2: half-wave split over k, lanes 0..31 own output cols
    const int c = lane & 31;
    const int half = lane >> 5;
    const float* hw = &hrow[wv][half * 64];
    const float* wp = &w2s[(size_t)half * 64 * NCLASS + c];
    float acc = 0.f;
#pragma unroll
    for (int k = 0; k < 64; ++k)
        acc += hw[k] * wp[k * NCLASS];
    acc += __shfl(acc, lane ^ 32);
    float accb = acc + b2[c];
    float nb = __shfl(accb, lane ^ 1);
    if (half == 0 && (lane & 1) == 0) {
        unsigned u = (unsigned)f2bf(accb) | ((unsigned)f2bf(nb) << 16);
        h2b[(size_t)row * 16 + (lane >> 1)] = u;
    }
}

// ---------------------------------------------------------------- SpMM2
// h2b bf16 [N][32] = 16 dwords/row; 16 lanes per row, 16 rows/block
__global__ __launch_bounds__(256) void spmm2_kernel(
    const int* __restrict__ row_ptr, const uint2* __restrict__ csr_e,
    const unsigned* __restrict__ h2b, float* __restrict__ out, int N)
{
    const int li = threadIdx.x & 15;
    const int g = threadIdx.x >> 4;
    const int row = blockIdx.x * 16 + g;
    if (row >= N) return;
    const int e0 = row_ptr[row], e1 = row_ptr[row + 1];
    float a0 = 0.f, a1 = 0.f;
    int e = e0;
    for (; e + 8 <= e1; e += 8) {
        uint2 r[8];
#pragma unroll
        for (int j = 0; j < 8; ++j) r[j] = csr_e[e + j];
        unsigned d[8];
#pragma unroll
        for (int j = 0; j < 8; ++j) d[j] = h2b[(size_t)r[j].x * 16 + li];
#pragma unroll
        for (int j = 0; j < 8; ++j) {
            float w = __uint_as_float(r[j].y);
            a0 += w * bf_lo(d[j]); a1 += w * bf_hi(d[j]);
        }
    }
    for (; e + 2 <= e1; e += 2) {
        uint2 r0 = csr_e[e], r1 = csr_e[e + 1];
        unsigned d0 = h2b[(size_t)r0.x * 16 + li];
        unsigned d1 = h2b[(size_t)r1.x * 16 + li];
        float w0 = __uint_as_float(r0.y), w1 = __uint_as_float(r1.y);
        a0 += w0 * bf_lo(d0); a1 += w0 * bf_hi(d0);
        a0 += w1 * bf_lo(d1); a1 += w1 * bf_hi(d1);
    }
    if (e < e1) {
        uint2 r = csr_e[e];
        float w = __uint_as_float(r.y);
        unsigned d = h2b[(size_t)r.x * 16 + li];
        a0 += w * bf_lo(d); a1 += w * bf_hi(d);
    }
    *(float2*)&out[(size_t)row * NCLASS + li * 2] = make_float2(a0, a1);
}

// ---------------------------------------------------------------- launch

extern "C" void kernel_launch(void* const* d_in, const int* in_sizes, int n_in,
                              void* d_out, int out_size, void* d_ws, size_t ws_size,
                              hipStream_t stream) {
    const float* x    = (const float*)d_in[0];
    const int*   esrc = (const int*)d_in[1];
    const int*   edst = (const int*)d_in[2];
    const float* ew   = (const float*)d_in[3];
    const float* W1   = (const float*)d_in[4];
    const float* b1   = (const float*)d_in[5];
    const float* W2   = (const float*)d_in[6];
    const float* b2   = (const float*)d_in[7];
    float* out = (float*)d_out;

    const int N = in_sizes[0] / NFEAT;
    const int E = in_sizes[1];

    int shift = 0;
    while (((N - 1) >> shift) >= 256) ++shift;
    const int NBKT = ((N - 1) >> shift) + 1;

    char* base = (char*)d_ws;
    size_t off = 0;
    auto take = [&](size_t bytes) -> void* {
        void* p = base + off;
        off += (bytes + 255) & ~(size_t)255;
        return p;
    };
    unsigned short* h1b = (unsigned short*)take((size_t)N * NHID * sizeof(unsigned short));
    unsigned* h2b  = (unsigned*)take((size_t)N * 16 * sizeof(unsigned));
    int*   row_ptr = (int*)take((size_t)(N + 1) * sizeof(int));
    int*   bkt_partial = (int*)take(256 * 256 * sizeof(int));
    int*   bkt_base    = (int*)take(257 * sizeof(int));
    int*   bkt_cursor  = (int*)take(256 * sizeof(int));
    uint2* bkt_edges   = (uint2*)take((size_t)E * sizeof(uint2));
    uint2* csr_e       = (uint2*)take((size_t)E * sizeof(uint2));
    unsigned short* W1t = (unsigned short*)take((size_t)NFEAT * NHID * sizeof(unsigned short));
    (void)ws_size; (void)n_in; (void)out_size;

    prep_kernel<<<384, 256, 0, stream>>>(W1, W1t, edst, bkt_partial, E, shift);
    gemm1_mfma_kernel<<<(N + 63) / 64, 256, 0, stream>>>(x, W1t, b1, h1b, N);
    bucket_scan_kernel<<<1, 256, 0, stream>>>(bkt_partial, bkt_base, bkt_cursor);
    bucket_scatter_kernel<<<(E + 256 * SC_EPT - 1) / (256 * SC_EPT), 256, 0, stream>>>(
        esrc, edst, ew, bkt_cursor, bkt_edges, E, shift);
    fine_scatter_kernel<<<NBKT, 256, 0, stream>>>(bkt_base, bkt_edges, row_ptr, csr_e,
                                                  shift, N, E);
    spmm1_gemm2_kernel<<<(N + 7) / 8, 512, 0, stream>>>(row_ptr, csr_e, h1b, W2, b2, h2b, N);
    spmm2_kernel<<<(N + 15) / 16, 256, 0, stream>>>(row_ptr, csr_e, h2b, out, N);
}